// Round 3
// baseline (556.332 us; speedup 1.0000x reference)
//
#include <hip/hip_runtime.h>
#include <hip/hip_bf16.h>

typedef __hip_bfloat16 bf16;
typedef __attribute__((ext_vector_type(8))) short short8;
typedef __attribute__((ext_vector_type(4))) float float4v;

static __device__ __forceinline__ float b2f(bf16 x) { return __bfloat162float(x); }

// dtype-dispatched load/store: f32=1 -> buffer is float32, f32=0 -> bfloat16.
static __device__ __forceinline__ float ldf(const void* p, size_t i, int f32) {
    return f32 ? ((const float*)p)[i] : b2f(((const bf16*)p)[i]);
}
static __device__ __forceinline__ void stf(void* p, size_t i, int f32, float v) {
    if (f32) ((float*)p)[i] = v;
    else     ((bf16*)p)[i] = __float2bfloat16(v);
}
static __device__ __forceinline__ unsigned short f2bf_bits(float f) {
    bf16 h = __float2bfloat16(f);
    return *(unsigned short*)&h;
}

// fast tanh: 1 - 2/(e^2x + 1)
static __device__ __forceinline__ float fast_tanh(float x) {
    float t = __expf(2.f * x);
    return 1.f - 2.f * __builtin_amdgcn_rcpf(t + 1.f);
}

// ---------------- dtype detector ----------------
__global__ void detect_kernel(const unsigned short* __restrict__ a, int* __restrict__ flag)
{
    __shared__ int cnt;
    if (threadIdx.x == 0) cnt = 0;
    __syncthreads();
    unsigned e = (a[threadIdx.x] >> 7) & 0xFF;
    if (e < 100 || e > 133) atomicAdd(&cnt, 1);
    __syncthreads();
    if (threadIdx.x == 0) *flag = (cnt >= 16) ? 1 : 0;   // 1 => float32 tensors
}

// ---------------- small prep: W transposes + M/c32/cvals + We^T precompute --------------
// blocks 0..5: 64x64 W transpose; 6..7: 64x32 Wr transpose; 8..9: per-relation precompute
// block 10: wet[n*16+k] = bf16(We[k*64+n])  (64x16, for the edge-MLP MFMA B-fragments)
__global__ __launch_bounds__(256) void prep_small_kernel(
    const void* __restrict__ W0, const void* __restrict__ W1,
    const void* __restrict__ W2, const void* __restrict__ W3,
    const void* __restrict__ W4, const void* __restrict__ W5,
    const void* __restrict__ Wr_a, const void* __restrict__ Wr_b,
    const void* __restrict__ We,
    const void* __restrict__ Wo_a, const void* __restrict__ Wo_b,
    const void* __restrict__ rel1, const void* __restrict__ rel2,
    const void* __restrict__ a_attn, const int* __restrict__ flagp,
    unsigned short* __restrict__ wt,
    float* __restrict__ M1, float* __restrict__ c321,
    float* __restrict__ M2, float* __restrict__ c322,
    float* __restrict__ cvals)
{
    const int f32 = *flagp;
    const int bid = blockIdx.x;
    if (bid < 6) {
        const void* src;
        switch (bid) {
            case 0: src = W0; break; case 1: src = W1; break; case 2: src = W2; break;
            case 3: src = W3; break; case 4: src = W4; break; default: src = W5; break;
        }
        unsigned short* dst = wt + bid * 4096;
        for (int i = threadIdx.x; i < 4096; i += 256) {
            int c = i >> 6, j = i & 63;
            dst[j * 64 + c] = f2bf_bits(ldf(src, c * 64 + j, f32));
        }
    } else if (bid < 8) {
        const void* src = (bid == 6) ? Wr_a : Wr_b;
        unsigned short* dst = wt + 24576 + (bid - 6) * 2048;
        for (int i = threadIdx.x; i < 2048; i += 256) {
            int c = i >> 5, j = i & 31;          // c: 64 in-rows, j: 32 out-cols
            dst[j * 64 + c] = f2bf_bits(ldf(src, c * 32 + j, f32));
        }
    } else if (bid < 10) {
        const int sel = bid - 8;                 // 0: rel1/Wo_b, 1: rel2/Wo_a
        const void* Wo  = sel ? Wo_a : Wo_b;
        const void* rel = sel ? rel2 : rel1;
        float* M   = sel ? M2 : M1;
        float* c32 = sel ? c322 : c321;
        const int t = threadIdx.x;
        for (int i = t; i < 1024; i += 256) {
            int m = i >> 5, j = i & 31;
            int h = m >> 4, c = m & 15;
            float s = 0.f;
            for (int jj = 0; jj < 32; ++jj)
                s += ldf(We, c * 64 + h * 32 + jj, f32) * ldf(Wo, (size_t)(h * 32 + jj) * 32 + j, f32);
            M[m * 32 + j] = s;
        }
        if (t < 32) {
            float s2 = 0.f;
            for (int ch = 0; ch < 64; ++ch)
                s2 += ldf(rel, ch, f32) * ldf(Wo, (size_t)ch * 32 + t, f32);
            c32[t] = s2;
        }
        if (t == 252 || t == 253) {
            int h = t - 252;
            float s3 = 0.f;
            for (int l = 0; l < 32; ++l)
                s3 += tanhf(ldf(rel, h * 32 + l, f32)) * ldf(a_attn, 64 + l, f32);
            cvals[sel * 2 + h] = s3;
        }
    } else {
        unsigned short* wet = wt + 28672;
        for (int i = threadIdx.x; i < 1024; i += 256) {
            int n = i >> 4, k = i & 15;
            wet[n * 16 + k] = f2bf_bits(ldf(We, k * 64 + n, f32));
        }
    }
}

// ---------------- node prep (MFMA): q/k scores, v (bf16), r = x@Wr ----------------
__global__ __launch_bounds__(256) void node_prep_mfma_kernel(
    const void* __restrict__ x_a, const void* __restrict__ x_b,
    const unsigned short* __restrict__ wt,
    const void* __restrict__ emb_a, const void* __restrict__ emb_b,
    const void* __restrict__ a_attn, const int* __restrict__ flagp,
    unsigned short* __restrict__ v_a, unsigned short* __restrict__ v_b,
    float* __restrict__ r_a, float* __restrict__ r_b,
    float* __restrict__ sq_a, float* __restrict__ sk_a,
    float* __restrict__ sq_b, float* __restrict__ sk_b,
    int n_nodes, int tiles)
{
    const int f32 = *flagp;
    const int wave_id = blockIdx.x * 4 + (threadIdx.x >> 6);
    if (wave_id >= 2 * tiles) return;
    const int type = (wave_id >= tiles);
    const int tile = type ? (wave_id - tiles) : wave_id;

    const void* xp = type ? x_b : x_a;
    const unsigned short* wq = wt + (type ? 3 * 4096 : 0);
    const unsigned short* wk = wq + 4096;
    const unsigned short* wv = wk + 4096;
    const unsigned short* wr = wt + 24576 + (type ? 2048 : 0);
    const void* embp = type ? emb_b : emb_a;
    unsigned short* v_out = type ? v_b : v_a;
    float*  r_out  = type ? r_b : r_a;
    float2* sq_out = (float2*)(type ? sq_b : sq_a);
    float2* sk_out = (float2*)(type ? sk_b : sk_a);

    const int lane = threadIdx.x & 63;
    const int ml   = lane & 15;        // node-row (A) / out-col (B,D)
    const int g    = lane >> 4;        // quad
    const int g8   = g * 8;

    float embc[4], acq[4], ack[4];
    #pragma unroll
    for (int t = 0; t < 4; ++t) {
        int colt = t * 16 + ml;
        embc[t] = ldf(embp, colt, f32);
        acq[t]  = ldf(a_attn, colt & 31, f32);
        ack[t]  = ldf(a_attn, 32 + (colt & 31), f32);
    }

    short8 Bq[4][2], Bk[4][2], Bv[4][2], Br[2][2];
    #pragma unroll
    for (int t = 0; t < 4; ++t) {
        const int rowo = (t * 16 + ml) * 64;
        #pragma unroll
        for (int kh = 0; kh < 2; ++kh) {
            const int o = rowo + kh * 32 + g8;
            Bq[t][kh] = __builtin_bit_cast(short8, *(const uint4*)(wq + o));
            Bk[t][kh] = __builtin_bit_cast(short8, *(const uint4*)(wk + o));
            Bv[t][kh] = __builtin_bit_cast(short8, *(const uint4*)(wv + o));
            if (t < 2)
                Br[t][kh] = __builtin_bit_cast(short8, *(const uint4*)(wr + o));
        }
    }

    const int n0 = tile << 4;
    int nr = n0 + ml; if (nr > n_nodes - 1) nr = n_nodes - 1;
    short8 A0, A1;
    if (f32) {
        const float4* xr = (const float4*)((const float*)xp + (size_t)nr * 64);
        float4 f0 = xr[2*g], f1 = xr[2*g+1], f2 = xr[8+2*g], f3 = xr[9+2*g];
        short8 a0, a1;
        a0[0]=(short)f2bf_bits(f0.x); a0[1]=(short)f2bf_bits(f0.y);
        a0[2]=(short)f2bf_bits(f0.z); a0[3]=(short)f2bf_bits(f0.w);
        a0[4]=(short)f2bf_bits(f1.x); a0[5]=(short)f2bf_bits(f1.y);
        a0[6]=(short)f2bf_bits(f1.z); a0[7]=(short)f2bf_bits(f1.w);
        a1[0]=(short)f2bf_bits(f2.x); a1[1]=(short)f2bf_bits(f2.y);
        a1[2]=(short)f2bf_bits(f2.z); a1[3]=(short)f2bf_bits(f2.w);
        a1[4]=(short)f2bf_bits(f3.x); a1[5]=(short)f2bf_bits(f3.y);
        a1[6]=(short)f2bf_bits(f3.z); a1[7]=(short)f2bf_bits(f3.w);
        A0 = a0; A1 = a1;
    } else {
        const uint4* xr = (const uint4*)((const bf16*)xp + (size_t)nr * 64);
        A0 = __builtin_bit_cast(short8, xr[g]);
        A1 = __builtin_bit_cast(short8, xr[4 + g]);
    }

    float4v accq[4], acck[4], accv[4], accr[2];
    #pragma unroll
    for (int t = 0; t < 4; ++t) {
        float4v z = {0.f, 0.f, 0.f, 0.f};
        accq[t] = z; acck[t] = z; accv[t] = z;
        if (t < 2) accr[t] = z;
    }
    #pragma unroll
    for (int t = 0; t < 4; ++t) {
        accq[t] = __builtin_amdgcn_mfma_f32_16x16x32_bf16(A0, Bq[t][0], accq[t], 0, 0, 0);
        accq[t] = __builtin_amdgcn_mfma_f32_16x16x32_bf16(A1, Bq[t][1], accq[t], 0, 0, 0);
        acck[t] = __builtin_amdgcn_mfma_f32_16x16x32_bf16(A0, Bk[t][0], acck[t], 0, 0, 0);
        acck[t] = __builtin_amdgcn_mfma_f32_16x16x32_bf16(A1, Bk[t][1], acck[t], 0, 0, 0);
        accv[t] = __builtin_amdgcn_mfma_f32_16x16x32_bf16(A0, Bv[t][0], accv[t], 0, 0, 0);
        accv[t] = __builtin_amdgcn_mfma_f32_16x16x32_bf16(A1, Bv[t][1], accv[t], 0, 0, 0);
        if (t < 2) {
            accr[t] = __builtin_amdgcn_mfma_f32_16x16x32_bf16(A0, Br[t][0], accr[t], 0, 0, 0);
            accr[t] = __builtin_amdgcn_mfma_f32_16x16x32_bf16(A1, Br[t][1], accr[t], 0, 0, 0);
        }
    }

    #pragma unroll
    for (int t = 0; t < 4; ++t) {
        #pragma unroll
        for (int r = 0; r < 4; ++r) {
            int node = n0 + g * 4 + r;
            if (node < n_nodes) {
                v_out[(size_t)node * 64 + t * 16 + ml] = f2bf_bits(accv[t][r]);
                if (t < 2) r_out[(size_t)node * 32 + t * 16 + ml] = accr[t][r];
            }
        }
    }

    #pragma unroll
    for (int r = 0; r < 4; ++r) {
        float q0 = fast_tanh(accq[0][r] + embc[0]) * acq[0]
                 + fast_tanh(accq[1][r] + embc[1]) * acq[1];
        float q1 = fast_tanh(accq[2][r] + embc[2]) * acq[2]
                 + fast_tanh(accq[3][r] + embc[3]) * acq[3];
        float k0 = fast_tanh(acck[0][r] + embc[0]) * ack[0]
                 + fast_tanh(acck[1][r] + embc[1]) * ack[1];
        float k1 = fast_tanh(acck[2][r] + embc[2]) * ack[2]
                 + fast_tanh(acck[3][r] + embc[3]) * ack[3];
        #pragma unroll
        for (int o = 1; o < 16; o <<= 1) {
            q0 += __shfl_xor(q0, o, 64); q1 += __shfl_xor(q1, o, 64);
            k0 += __shfl_xor(k0, o, 64); k1 += __shfl_xor(k1, o, 64);
        }
        int node = n0 + g * 4 + r;
        if (ml == 0 && node < n_nodes) {
            sq_out[node] = make_float2(q0, q1);
            sk_out[node] = make_float2(k0, k1);
        }
    }
}

// ---------------- CSR build ----------------
__global__ __launch_bounds__(256) void hist_kernel(
    const int* __restrict__ col1, const int* __restrict__ col2,
    int* __restrict__ cnt, int n_nodes, int num_e)
{
    const int sel = blockIdx.x & 1;
    const int bx  = blockIdx.x >> 1;
    const int* col = sel ? col2 : col1;
    const int rb = sel ? n_nodes : 0;
    int e = bx * 256 + threadIdx.x;
    if (e < num_e) atomicAdd(&cnt[rb + col[e]], 1);
}

__global__ __launch_bounds__(256) void scan1_kernel(const int* __restrict__ cnt,
                                                    int* __restrict__ partial, int n)
{
    __shared__ int wsum[4];
    int t = threadIdx.x;
    int i0 = blockIdx.x * 512 + 2 * t;
    int s = ((i0 < n) ? cnt[i0] : 0) + ((i0 + 1 < n) ? cnt[i0 + 1] : 0);
    #pragma unroll
    for (int o = 32; o; o >>= 1) s += __shfl_xor(s, o, 64);
    if ((t & 63) == 0) wsum[t >> 6] = s;
    __syncthreads();
    if (t == 0) partial[blockIdx.x] = wsum[0] + wsum[1] + wsum[2] + wsum[3];
}

__global__ void scan2_kernel(const int* __restrict__ partial, int* __restrict__ pp,
                             int* __restrict__ off, int nch, int noff)
{
    int lane = threadIdx.x;   // 64 threads
    int running = 0;
    for (int base = 0; base < nch; base += 64) {
        int i = base + lane;
        int o = (i < nch) ? partial[i] : 0;
        int v = o;
        #pragma unroll
        for (int d = 1; d < 64; d <<= 1) {
            int u = __shfl_up(v, d, 64);
            if (lane >= d) v += u;
        }
        if (i < nch) pp[i] = running + v - o;
        running += __shfl(v, 63, 64);
    }
    if (lane == 0) off[noff] = running;
}

__global__ __launch_bounds__(256) void scan3_kernel(const int* __restrict__ cnt,
                                                    const int* __restrict__ pp,
                                                    int* __restrict__ off,
                                                    int* __restrict__ cursor, int n)
{
    __shared__ int tmp[256];
    int t = threadIdx.x;
    int i0 = blockIdx.x * 512 + 2 * t;
    int v0 = (i0 < n) ? cnt[i0] : 0;
    int v1 = (i0 + 1 < n) ? cnt[i0 + 1] : 0;
    int pair = v0 + v1;
    tmp[t] = pair;
    __syncthreads();
    for (int d = 1; d < 256; d <<= 1) {
        int x = (t >= d) ? tmp[t - d] : 0;
        __syncthreads();
        tmp[t] += x;
        __syncthreads();
    }
    int excl = tmp[t] - pair + pp[blockIdx.x];
    if (i0 < n)     { off[i0] = excl;          cursor[i0] = excl; }
    if (i0 + 1 < n) { off[i0 + 1] = excl + v0; cursor[i0 + 1] = excl + v0; }
}

// ---------------- fused edge scores + scatter, MFMA MLP (both relations, XCD-split) -----
// Per wave-iteration: 16 edges. A-frag = bf16 ea channels (K=32, upper half zero),
// B-frag = We^T (wet). 4 MFMAs give eb[16 edges][64]; tanh+a4 reduced by a 16-lane
// butterfly. 16 finalize lanes do gather/atomic; payload ea halves are the A-frags.
// 48B CSR record per edge: {src, ex0, ex1, pad, ea[16] bf16}
__global__ __launch_bounds__(256) void edge_score_scatter_kernel(
    const void* __restrict__ ea1p, const void* __restrict__ ea2p,
    const unsigned short* __restrict__ wet,
    const int* __restrict__ row1, const int* __restrict__ col1,
    const int* __restrict__ row2, const int* __restrict__ col2,
    const float* __restrict__ sq_bp, const float* __restrict__ sk_ap,
    const float* __restrict__ sq_ap, const float* __restrict__ sk_bp,
    const float* __restrict__ cvals, const void* __restrict__ a_attn,
    const int* __restrict__ flagp, int* __restrict__ cursor,
    uint4* __restrict__ payload, int n_nodes, int num_e)
{
    const int f32 = *flagp;
    const int sel = blockIdx.x & 1;
    const int bx  = blockIdx.x >> 1;
    const void* ea = sel ? ea2p : ea1p;
    const int* row = sel ? row2 : row1;
    const int* col = sel ? col2 : col1;
    const float* sq_dst = sel ? sq_ap : sq_bp;
    const float* sk_src = sel ? sk_bp : sk_ap;
    const int rb = sel ? n_nodes : 0;

    const int lane = threadIdx.x & 63;
    const int wv   = threadIdx.x >> 6;
    const int ml   = lane & 15;
    const int g    = lane >> 4;

    const short8 zero8 = {0, 0, 0, 0, 0, 0, 0, 0};

    // B-fragments: B[k][n=t*16+ml], k = g*8..g*8+7 (<16 real, else 0)
    short8 B[4];
    #pragma unroll
    for (int t = 0; t < 4; ++t)
        B[t] = (g < 2) ? __builtin_bit_cast(short8, *(const uint4*)(wet + (t * 16 + ml) * 16 + g * 8))
                       : zero8;
    float av[4];
    #pragma unroll
    for (int t = 0; t < 4; ++t) av[t] = ldf(a_attn, 96 + ((t * 16 + ml) & 31), f32);
    const float c0 = cvals[sel * 2 + 0];
    const float c1 = cvals[sel * 2 + 1];

    const int base = bx * 512 + wv * 128;
    #pragma unroll 1
    for (int it = 0; it < 8; ++it) {
        const int e0 = base + it * 16;
        if (e0 >= num_e) break;                       // uniform per wave

        int ec = e0 + ml; if (ec > num_e - 1) ec = num_e - 1;
        short8 A = zero8;
        if (g < 2) {
            if (f32) {
                const float4* p = (const float4*)((const float*)ea + (size_t)ec * 16 + g * 8);
                float4 f0 = p[0], f1 = p[1];
                short8 a;
                a[0] = (short)f2bf_bits(f0.x); a[1] = (short)f2bf_bits(f0.y);
                a[2] = (short)f2bf_bits(f0.z); a[3] = (short)f2bf_bits(f0.w);
                a[4] = (short)f2bf_bits(f1.x); a[5] = (short)f2bf_bits(f1.y);
                a[6] = (short)f2bf_bits(f1.z); a[7] = (short)f2bf_bits(f1.w);
                A = a;
            } else {
                A = __builtin_bit_cast(short8, *(const uint4*)((const bf16*)ea + (size_t)ec * 16 + g * 8));
            }
        }

        float4v z = {0.f, 0.f, 0.f, 0.f};
        float4v acc0 = z, acc1 = z, acc2 = z, acc3 = z;
        acc0 = __builtin_amdgcn_mfma_f32_16x16x32_bf16(A, B[0], acc0, 0, 0, 0);
        acc1 = __builtin_amdgcn_mfma_f32_16x16x32_bf16(A, B[1], acc1, 0, 0, 0);
        acc2 = __builtin_amdgcn_mfma_f32_16x16x32_bf16(A, B[2], acc2, 0, 0, 0);
        acc3 = __builtin_amdgcn_mfma_f32_16x16x32_bf16(A, B[3], acc3, 0, 0, 0);

        // per-lane partials: s0/s1[r] for edges g*4+r, heads 0/1
        float s0[4], s1[4];
        #pragma unroll
        for (int r = 0; r < 4; ++r) {
            s0[r] = fast_tanh(acc0[r]) * av[0] + fast_tanh(acc1[r]) * av[1];
            s1[r] = fast_tanh(acc2[r]) * av[2] + fast_tanh(acc3[r]) * av[3];
        }
        // butterfly over the 16-lane column group: all lanes end with full sums
        #pragma unroll
        for (int o = 1; o < 16; o <<= 1) {
            #pragma unroll
            for (int r = 0; r < 4; ++r) {
                s0[r] += __shfl_xor(s0[r], o, 64);
                s1[r] += __shfl_xor(s1[r], o, 64);
            }
        }

        // finalize lanes: (lane&15)<4 -> edge g*4 + (lane&3)
        int pos = 0;
        float ex0 = 0.f, ex1 = 0.f;
        unsigned srcn = 0;
        const int rsel = lane & 3;
        const int eidx = g * 4 + rsel;
        const bool fin = (ml < 4) && (e0 + eidx < num_e);
        if (fin) {
            float a0 = (rsel == 0) ? s0[0] : (rsel == 1) ? s0[1] : (rsel == 2) ? s0[2] : s0[3];
            float a1 = (rsel == 0) ? s1[0] : (rsel == 1) ? s1[1] : (rsel == 2) ? s1[2] : s1[3];
            const int e = e0 + eidx;
            const int dc = col[e];
            srcn = (unsigned)row[e];
            float2 sqd = ((const float2*)sq_dst)[dc];
            float2 sks = ((const float2*)sk_src)[srcn];
            float v0 = fminf(30.f, fmaxf(-30.f, a0 + sqd.x + sks.x + c0));
            float v1 = fminf(30.f, fmaxf(-30.f, a1 + sqd.y + sks.y + c1));
            ex0 = __expf(v0); ex1 = __expf(v1);
            pos = atomicAdd(&cursor[rb + dc], 1);
        }
        // broadcast pos: writer lane l (<32) targets edge ml=l&15; its finalize
        // lane is ((ml>>2)*16 + (ml&3)) = ((l&12)<<2) | (l&3)
        const int srcl = ((lane & 12) << 2) | (lane & 3);
        const int posx = __shfl(pos, srcl, 64);
        if (fin) {
            uint4* rec = payload + (size_t)3 * pos;
            rec[0] = make_uint4(srcn, __float_as_uint(ex0), __float_as_uint(ex1), 0u);
        }
        if (lane < 32 && (e0 + ml < num_e)) {
            uint4* rec = payload + (size_t)3 * posx;
            rec[1 + g] = __builtin_bit_cast(uint4, A);   // ea channels g*8..g*8+7 (bf16)
        }
    }
}

// ---------------- fused aggregation + output projection (both relations, XCD-split) -----
__global__ __launch_bounds__(256) void agg_final_kernel(
    const uint4* __restrict__ payload, const int* __restrict__ off,
    const unsigned short* __restrict__ v_a, const unsigned short* __restrict__ v_b,
    const float* __restrict__ r_a, const float* __restrict__ r_b,
    const void* __restrict__ Wo_a, const void* __restrict__ Wo_b,
    const void* __restrict__ bo_a, const void* __restrict__ bo_b,
    const float* __restrict__ M1, const float* __restrict__ M2,
    const float* __restrict__ c321, const float* __restrict__ c322,
    const int* __restrict__ flagp, void* __restrict__ out,
    int n_nodes, int nbh)
{
    const int sel = blockIdx.x & 1;                 // 0: rel1 (dst=b), 1: rel2 (dst=a)
    const int bx  = blockIdx.x >> 1;
    const unsigned short* v_src = sel ? v_b : v_a;
    const float* r_src = sel ? r_a : r_b;           // residual of DST type
    const void*  Wo    = sel ? Wo_a : Wo_b;
    const void*  bo    = sel ? bo_a : bo_b;
    const float* M     = sel ? M2 : M1;
    const float* c32   = sel ? c322 : c321;
    const int relbase  = sel ? n_nodes : 0;
    const size_t out_off = sel ? 0 : (size_t)n_nodes * 32;

    const int f32  = *flagp;
    const int lane = threadIdx.x & 63;
    const int wv   = threadIdx.x >> 6;
    const int j    = lane & 31;
    const int half = lane >> 5;
    const int c16  = lane & 15;
    const bool hi  = (lane >= 32);

    __shared__ float stage[4][96];   // per-wave: y[64] | u[32]

    float WoR[32], MR[16];
    const int cb = half * 32;
    #pragma unroll
    for (int cc = 0; cc < 32; ++cc)
        WoR[cc] = ldf(Wo, (size_t)(cb + cc) * 32 + j, f32);
    const int ub = half * 16;
    #pragma unroll
    for (int cc = 0; cc < 16; ++cc) MR[cc] = M[(ub + cc) * 32 + j];
    const float boR  = ldf(bo, j, f32);
    const float c32R = c32[j];

    const int stride = nbh * 4;
    const int iters  = (n_nodes + stride - 1) / stride;
    int d = bx * 4 + wv;

    for (int it = 0; it < iters; ++it, d += stride) {
        const bool valid = (d < n_nodes);
        const int dd  = valid ? d : (n_nodes - 1);
        const int idx = relbase + dd;
        const int b   = __builtin_amdgcn_readfirstlane(off[idx]);
        const int en  = __builtin_amdgcn_readfirstlane(off[idx + 1]);
        const int deg = en - b;

        const float rv = r_src[(size_t)dd * 32 + j];   // early: overlaps edge loop

        float den0 = 0.f, den1 = 0.f, y = 0.f, ua = 0.f;
        int k = b;
        #pragma unroll 1
        for (; k + 8 <= en; k += 8) {
            uint4 m[8];
            #pragma unroll
            for (int q = 0; q < 8; ++q) m[q] = payload[(size_t)3 * (k + q)];
            float ev[8];
            #pragma unroll
            for (int q = 0; q < 8; ++q) {
                const unsigned short* pq = (const unsigned short*)(payload + (size_t)3 * (k + q) + 1);
                ev[q] = __uint_as_float((unsigned)pq[c16] << 16);
            }
            float vv[8];
            #pragma unroll
            for (int q = 0; q < 8; ++q)
                vv[q] = __uint_as_float((unsigned)v_src[(size_t)m[q].x * 64 + lane] << 16);
            #pragma unroll
            for (int q = 0; q < 8; ++q) {
                float e0 = __uint_as_float(m[q].y), e1 = __uint_as_float(m[q].z);
                den0 += e0; den1 += e1;
                float xw = hi ? e1 : e0;
                y  = fmaf(xw, vv[q], y);
                ua = fmaf(xw, ev[q], ua);
            }
        }
        #pragma unroll 1
        for (; k < en; ++k) {
            uint4 mm = payload[(size_t)3 * k];
            const unsigned short* pq = (const unsigned short*)(payload + (size_t)3 * k + 1);
            float evs = __uint_as_float((unsigned)pq[c16] << 16);
            float vvs = __uint_as_float((unsigned)v_src[(size_t)mm.x * 64 + lane] << 16);
            float e0 = __uint_as_float(mm.y), e1 = __uint_as_float(mm.z);
            den0 += e0; den1 += e1;
            float xw = hi ? e1 : e0;
            y  = fmaf(xw, vvs, y);
            ua = fmaf(xw, evs, ua);
        }

        float inv0 = (deg > 0) ? __builtin_amdgcn_rcpf(den0) : 0.f;
        float inv1 = (deg > 0) ? __builtin_amdgcn_rcpf(den1) : 0.f;
        const float invh = hi ? inv1 : inv0;
        y  *= invh;
        ua *= invh;

        // wave-private LDS staging (lockstep wave64 + lgkmcnt drain).
        float* st = stage[wv];
        st[lane] = y;
        if ((lane & 31) < 16) st[64 + half * 16 + c16] = ua;
        __asm__ volatile("s_waitcnt lgkmcnt(0)" ::: "memory");

        float acc = 0.f;
        #pragma unroll
        for (int cc = 0; cc < 32; ++cc)
            acc = fmaf(st[cb + cc], WoR[cc], acc);
        #pragma unroll
        for (int cc = 0; cc < 16; ++cc)
            acc = fmaf(st[64 + ub + cc], MR[cc], acc);

        float other = __shfl(acc, lane ^ 32, 64);
        if (valid && lane < 32) {
            float o = acc + other + boR + rv + ((deg > 0) ? c32R : 0.f);
            stf(out, out_off + (size_t)dd * 32 + j, f32, o);
        }
        __asm__ volatile("" ::: "memory");
        __builtin_amdgcn_wave_barrier();
    }
}

extern "C" void kernel_launch(void* const* d_in, const int* in_sizes, int n_in,
                              void* d_out, int out_size, void* d_ws, size_t ws_size,
                              hipStream_t stream)
{
    const void* x_a   = d_in[0];
    const void* x_b   = d_in[1];
    const void* ea1   = d_in[2];
    const void* ea2   = d_in[3];
    const void* Wq_a  = d_in[4];
    const void* Wk_a  = d_in[5];
    const void* Wv_a  = d_in[6];
    const void* Wq_b  = d_in[7];
    const void* Wk_b  = d_in[8];
    const void* Wv_b  = d_in[9];
    const void* emb_a = d_in[10];
    const void* emb_b = d_in[11];
    const void* rel1  = d_in[12];
    const void* rel2  = d_in[13];
    const void* We    = d_in[14];
    const void* a_at  = d_in[15];
    const void* Wo_a  = d_in[16];
    const void* bo_a  = d_in[17];
    const void* Wo_b  = d_in[18];
    const void* bo_b  = d_in[19];
    const void* Wr_a  = d_in[20];
    const void* Wr_b  = d_in[21];
    const int*  row1  = (const int*)d_in[22];
    const int*  col1  = (const int*)d_in[23];
    const int*  row2  = (const int*)d_in[24];
    const int*  col2  = (const int*)d_in[25];

    const int N = in_sizes[0] / 64;   // nodes per type
    const int E = in_sizes[22];       // edges per relation

    // ---- workspace layout (float units) ----
    float* ws = (float*)d_ws;
    size_t off = 0;
    int*   flag = (int*)ws;        off += 64;
    unsigned short* v_a = (unsigned short*)(ws + off); off += (size_t)N * 32;  // bf16 N x 64
    unsigned short* v_b = (unsigned short*)(ws + off); off += (size_t)N * 32;
    float* r_a  = ws + off;        off += (size_t)N * 32;
    float* r_b  = ws + off;        off += (size_t)N * 32;
    float* sq_a = ws + off;        off += (size_t)N * 2;
    float* sk_a = ws + off;        off += (size_t)N * 2;
    float* sq_b = ws + off;        off += (size_t)N * 2;
    float* sk_b = ws + off;        off += (size_t)N * 2;
    float* cvals = ws + off;       off += 4;
    off = (off + 3) & ~(size_t)3;  // 16B align
    unsigned short* wt = (unsigned short*)(ws + off); off += 29696 / 2;  // 6x4096+2x2048+1024 bf16
    float* M1   = ws + off;        off += 1024;
    float* c321 = ws + off;        off += 32;
    float* M2   = ws + off;        off += 1024;
    float* c322 = ws + off;        off += 32;
    int*   cnt    = (int*)(ws + off);  off += (size_t)2 * N;
    int*   offs   = (int*)(ws + off);  off += (size_t)2 * N + 2;
    int*   cursor = (int*)(ws + off);  off += (size_t)2 * N;
    int*   partial = (int*)(ws + off); off += 512;
    int*   pp      = (int*)(ws + off); off += 512;
    off = (off + 3) & ~(size_t)3;     // 16B align for uint4
    uint4* payload = (uint4*)(ws + off); off += (size_t)2 * E * 12;  // 48B records

    const int tiles        = (N + 15) >> 4;
    const int mfma_blocks  = (2 * tiles + 3) / 4;
    const int score_blocks = (E + 511) / 512;
    const int eb_blocks    = (E + 255) / 256;
    const int nch          = (2 * N + 511) / 512;
    const int agg_half     = 2048;                      // blocks per relation

    detect_kernel<<<1, 128, 0, stream>>>((const unsigned short*)a_at, flag);
    hipMemsetAsync(cnt, 0, (size_t)2 * N * sizeof(int), stream);

    prep_small_kernel<<<11, 256, 0, stream>>>(
        Wq_a, Wk_a, Wv_a, Wq_b, Wk_b, Wv_b, Wr_a, Wr_b,
        We, Wo_a, Wo_b, rel1, rel2, a_at, flag,
        wt, M1, c321, M2, c322, cvals);

    node_prep_mfma_kernel<<<mfma_blocks, 256, 0, stream>>>(
        x_a, x_b, wt, emb_a, emb_b, a_at, flag,
        v_a, v_b, r_a, r_b, sq_a, sk_a, sq_b, sk_b, N, tiles);

    hist_kernel<<<2 * eb_blocks, 256, 0, stream>>>(col1, col2, cnt, N, E);
    scan1_kernel<<<nch, 256, 0, stream>>>(cnt, partial, 2 * N);
    scan2_kernel<<<1, 64, 0, stream>>>(partial, pp, offs, nch, 2 * N);
    scan3_kernel<<<nch, 256, 0, stream>>>(cnt, pp, offs, cursor, 2 * N);

    edge_score_scatter_kernel<<<2 * score_blocks, 256, 0, stream>>>(
        ea1, ea2, wt + 28672, row1, col1, row2, col2,
        sq_b, sk_a, sq_a, sk_b, cvals, a_at, flag,
        cursor, payload, N, E);

    agg_final_kernel<<<2 * agg_half, 256, 0, stream>>>(
        payload, offs, v_a, v_b, r_a, r_b, Wo_a, Wo_b, bo_a, bo_b,
        M1, M2, c321, c322, flag, d_out, N, agg_half);
}

// Round 4
// 542.054 us; speedup vs baseline: 1.0263x; 1.0263x over previous
//
#include <hip/hip_runtime.h>
#include <hip/hip_bf16.h>

typedef __hip_bfloat16 bf16;
typedef __attribute__((ext_vector_type(8))) short short8;
typedef __attribute__((ext_vector_type(4))) float float4v;

static __device__ __forceinline__ float b2f(bf16 x) { return __bfloat162float(x); }

// dtype-dispatched load/store: f32=1 -> buffer is float32, f32=0 -> bfloat16.
static __device__ __forceinline__ float ldf(const void* p, size_t i, int f32) {
    return f32 ? ((const float*)p)[i] : b2f(((const bf16*)p)[i]);
}
static __device__ __forceinline__ void stf(void* p, size_t i, int f32, float v) {
    if (f32) ((float*)p)[i] = v;
    else     ((bf16*)p)[i] = __float2bfloat16(v);
}
static __device__ __forceinline__ unsigned short f2bf_bits(float f) {
    bf16 h = __float2bfloat16(f);
    return *(unsigned short*)&h;
}

// fast tanh: 1 - 2/(e^2x + 1)
static __device__ __forceinline__ float fast_tanh(float x) {
    float t = __expf(2.f * x);
    return 1.f - 2.f * __builtin_amdgcn_rcpf(t + 1.f);
}

// ---------------- dtype detector ----------------
__global__ void detect_kernel(const unsigned short* __restrict__ a, int* __restrict__ flag)
{
    __shared__ int cnt;
    if (threadIdx.x == 0) cnt = 0;
    __syncthreads();
    unsigned e = (a[threadIdx.x] >> 7) & 0xFF;
    if (e < 100 || e > 133) atomicAdd(&cnt, 1);
    __syncthreads();
    if (threadIdx.x == 0) *flag = (cnt >= 16) ? 1 : 0;   // 1 => float32 tensors
}

// ---------------- small prep: W transposes + M/c32/cvals + We^T precompute --------------
// blocks 0..5: 64x64 W transpose; 6..7: 64x32 Wr transpose; 8..9: per-relation precompute
// block 10: wet[n*16+k] = bf16(We[k*64+n])  (64x16, for the edge-MLP MFMA B-fragments)
__global__ __launch_bounds__(256) void prep_small_kernel(
    const void* __restrict__ W0, const void* __restrict__ W1,
    const void* __restrict__ W2, const void* __restrict__ W3,
    const void* __restrict__ W4, const void* __restrict__ W5,
    const void* __restrict__ Wr_a, const void* __restrict__ Wr_b,
    const void* __restrict__ We,
    const void* __restrict__ Wo_a, const void* __restrict__ Wo_b,
    const void* __restrict__ rel1, const void* __restrict__ rel2,
    const void* __restrict__ a_attn, const int* __restrict__ flagp,
    unsigned short* __restrict__ wt,
    float* __restrict__ M1, float* __restrict__ c321,
    float* __restrict__ M2, float* __restrict__ c322,
    float* __restrict__ cvals)
{
    const int f32 = *flagp;
    const int bid = blockIdx.x;
    if (bid < 6) {
        const void* src;
        switch (bid) {
            case 0: src = W0; break; case 1: src = W1; break; case 2: src = W2; break;
            case 3: src = W3; break; case 4: src = W4; break; default: src = W5; break;
        }
        unsigned short* dst = wt + bid * 4096;
        for (int i = threadIdx.x; i < 4096; i += 256) {
            int c = i >> 6, j = i & 63;
            dst[j * 64 + c] = f2bf_bits(ldf(src, c * 64 + j, f32));
        }
    } else if (bid < 8) {
        const void* src = (bid == 6) ? Wr_a : Wr_b;
        unsigned short* dst = wt + 24576 + (bid - 6) * 2048;
        for (int i = threadIdx.x; i < 2048; i += 256) {
            int c = i >> 5, j = i & 31;          // c: 64 in-rows, j: 32 out-cols
            dst[j * 64 + c] = f2bf_bits(ldf(src, c * 32 + j, f32));
        }
    } else if (bid < 10) {
        const int sel = bid - 8;                 // 0: rel1/Wo_b, 1: rel2/Wo_a
        const void* Wo  = sel ? Wo_a : Wo_b;
        const void* rel = sel ? rel2 : rel1;
        float* M   = sel ? M2 : M1;
        float* c32 = sel ? c322 : c321;
        const int t = threadIdx.x;
        for (int i = t; i < 1024; i += 256) {
            int m = i >> 5, j = i & 31;
            int h = m >> 4, c = m & 15;
            float s = 0.f;
            for (int jj = 0; jj < 32; ++jj)
                s += ldf(We, c * 64 + h * 32 + jj, f32) * ldf(Wo, (size_t)(h * 32 + jj) * 32 + j, f32);
            M[m * 32 + j] = s;
        }
        if (t < 32) {
            float s2 = 0.f;
            for (int ch = 0; ch < 64; ++ch)
                s2 += ldf(rel, ch, f32) * ldf(Wo, (size_t)ch * 32 + t, f32);
            c32[t] = s2;
        }
        if (t == 252 || t == 253) {
            int h = t - 252;
            float s3 = 0.f;
            for (int l = 0; l < 32; ++l)
                s3 += tanhf(ldf(rel, h * 32 + l, f32)) * ldf(a_attn, 64 + l, f32);
            cvals[sel * 2 + h] = s3;
        }
    } else {
        unsigned short* wet = wt + 28672;
        for (int i = threadIdx.x; i < 1024; i += 256) {
            int n = i >> 4, k = i & 15;
            wet[n * 16 + k] = f2bf_bits(ldf(We, k * 64 + n, f32));
        }
    }
}

// ---------------- node prep (MFMA): q/k scores, v (bf16), r = x@Wr ----------------
__global__ __launch_bounds__(256) void node_prep_mfma_kernel(
    const void* __restrict__ x_a, const void* __restrict__ x_b,
    const unsigned short* __restrict__ wt,
    const void* __restrict__ emb_a, const void* __restrict__ emb_b,
    const void* __restrict__ a_attn, const int* __restrict__ flagp,
    unsigned short* __restrict__ v_a, unsigned short* __restrict__ v_b,
    float* __restrict__ r_a, float* __restrict__ r_b,
    float* __restrict__ sq_a, float* __restrict__ sk_a,
    float* __restrict__ sq_b, float* __restrict__ sk_b,
    int n_nodes, int tiles)
{
    const int f32 = *flagp;
    const int wave_id = blockIdx.x * 4 + (threadIdx.x >> 6);
    if (wave_id >= 2 * tiles) return;
    const int type = (wave_id >= tiles);
    const int tile = type ? (wave_id - tiles) : wave_id;

    const void* xp = type ? x_b : x_a;
    const unsigned short* wq = wt + (type ? 3 * 4096 : 0);
    const unsigned short* wk = wq + 4096;
    const unsigned short* wv = wk + 4096;
    const unsigned short* wr = wt + 24576 + (type ? 2048 : 0);
    const void* embp = type ? emb_b : emb_a;
    unsigned short* v_out = type ? v_b : v_a;
    float*  r_out  = type ? r_b : r_a;
    float2* sq_out = (float2*)(type ? sq_b : sq_a);
    float2* sk_out = (float2*)(type ? sk_b : sk_a);

    const int lane = threadIdx.x & 63;
    const int ml   = lane & 15;        // node-row (A) / out-col (B,D)
    const int g    = lane >> 4;        // quad
    const int g8   = g * 8;

    float embc[4], acq[4], ack[4];
    #pragma unroll
    for (int t = 0; t < 4; ++t) {
        int colt = t * 16 + ml;
        embc[t] = ldf(embp, colt, f32);
        acq[t]  = ldf(a_attn, colt & 31, f32);
        ack[t]  = ldf(a_attn, 32 + (colt & 31), f32);
    }

    short8 Bq[4][2], Bk[4][2], Bv[4][2], Br[2][2];
    #pragma unroll
    for (int t = 0; t < 4; ++t) {
        const int rowo = (t * 16 + ml) * 64;
        #pragma unroll
        for (int kh = 0; kh < 2; ++kh) {
            const int o = rowo + kh * 32 + g8;
            Bq[t][kh] = __builtin_bit_cast(short8, *(const uint4*)(wq + o));
            Bk[t][kh] = __builtin_bit_cast(short8, *(const uint4*)(wk + o));
            Bv[t][kh] = __builtin_bit_cast(short8, *(const uint4*)(wv + o));
            if (t < 2)
                Br[t][kh] = __builtin_bit_cast(short8, *(const uint4*)(wr + o));
        }
    }

    const int n0 = tile << 4;
    int nr = n0 + ml; if (nr > n_nodes - 1) nr = n_nodes - 1;
    short8 A0, A1;
    if (f32) {
        const float4* xr = (const float4*)((const float*)xp + (size_t)nr * 64);
        float4 f0 = xr[2*g], f1 = xr[2*g+1], f2 = xr[8+2*g], f3 = xr[9+2*g];
        short8 a0, a1;
        a0[0]=(short)f2bf_bits(f0.x); a0[1]=(short)f2bf_bits(f0.y);
        a0[2]=(short)f2bf_bits(f0.z); a0[3]=(short)f2bf_bits(f0.w);
        a0[4]=(short)f2bf_bits(f1.x); a0[5]=(short)f2bf_bits(f1.y);
        a0[6]=(short)f2bf_bits(f1.z); a0[7]=(short)f2bf_bits(f1.w);
        a1[0]=(short)f2bf_bits(f2.x); a1[1]=(short)f2bf_bits(f2.y);
        a1[2]=(short)f2bf_bits(f2.z); a1[3]=(short)f2bf_bits(f2.w);
        a1[4]=(short)f2bf_bits(f3.x); a1[5]=(short)f2bf_bits(f3.y);
        a1[6]=(short)f2bf_bits(f3.z); a1[7]=(short)f2bf_bits(f3.w);
        A0 = a0; A1 = a1;
    } else {
        const uint4* xr = (const uint4*)((const bf16*)xp + (size_t)nr * 64);
        A0 = __builtin_bit_cast(short8, xr[g]);
        A1 = __builtin_bit_cast(short8, xr[4 + g]);
    }

    float4v accq[4], acck[4], accv[4], accr[2];
    #pragma unroll
    for (int t = 0; t < 4; ++t) {
        float4v z = {0.f, 0.f, 0.f, 0.f};
        accq[t] = z; acck[t] = z; accv[t] = z;
        if (t < 2) accr[t] = z;
    }
    #pragma unroll
    for (int t = 0; t < 4; ++t) {
        accq[t] = __builtin_amdgcn_mfma_f32_16x16x32_bf16(A0, Bq[t][0], accq[t], 0, 0, 0);
        accq[t] = __builtin_amdgcn_mfma_f32_16x16x32_bf16(A1, Bq[t][1], accq[t], 0, 0, 0);
        acck[t] = __builtin_amdgcn_mfma_f32_16x16x32_bf16(A0, Bk[t][0], acck[t], 0, 0, 0);
        acck[t] = __builtin_amdgcn_mfma_f32_16x16x32_bf16(A1, Bk[t][1], acck[t], 0, 0, 0);
        accv[t] = __builtin_amdgcn_mfma_f32_16x16x32_bf16(A0, Bv[t][0], accv[t], 0, 0, 0);
        accv[t] = __builtin_amdgcn_mfma_f32_16x16x32_bf16(A1, Bv[t][1], accv[t], 0, 0, 0);
        if (t < 2) {
            accr[t] = __builtin_amdgcn_mfma_f32_16x16x32_bf16(A0, Br[t][0], accr[t], 0, 0, 0);
            accr[t] = __builtin_amdgcn_mfma_f32_16x16x32_bf16(A1, Br[t][1], accr[t], 0, 0, 0);
        }
    }

    #pragma unroll
    for (int t = 0; t < 4; ++t) {
        #pragma unroll
        for (int r = 0; r < 4; ++r) {
            int node = n0 + g * 4 + r;
            if (node < n_nodes) {
                v_out[(size_t)node * 64 + t * 16 + ml] = f2bf_bits(accv[t][r]);
                if (t < 2) r_out[(size_t)node * 32 + t * 16 + ml] = accr[t][r];
            }
        }
    }

    #pragma unroll
    for (int r = 0; r < 4; ++r) {
        float q0 = fast_tanh(accq[0][r] + embc[0]) * acq[0]
                 + fast_tanh(accq[1][r] + embc[1]) * acq[1];
        float q1 = fast_tanh(accq[2][r] + embc[2]) * acq[2]
                 + fast_tanh(accq[3][r] + embc[3]) * acq[3];
        float k0 = fast_tanh(acck[0][r] + embc[0]) * ack[0]
                 + fast_tanh(acck[1][r] + embc[1]) * ack[1];
        float k1 = fast_tanh(acck[2][r] + embc[2]) * ack[2]
                 + fast_tanh(acck[3][r] + embc[3]) * ack[3];
        #pragma unroll
        for (int o = 1; o < 16; o <<= 1) {
            q0 += __shfl_xor(q0, o, 64); q1 += __shfl_xor(q1, o, 64);
            k0 += __shfl_xor(k0, o, 64); k1 += __shfl_xor(k1, o, 64);
        }
        int node = n0 + g * 4 + r;
        if (ml == 0 && node < n_nodes) {
            sq_out[node] = make_float2(q0, q1);
            sk_out[node] = make_float2(k0, k1);
        }
    }
}

// ---------------- CSR build ----------------
__global__ __launch_bounds__(256) void hist_kernel(
    const int* __restrict__ col1, const int* __restrict__ col2,
    int* __restrict__ cnt, int n_nodes, int num_e)
{
    const int sel = blockIdx.x & 1;
    const int bx  = blockIdx.x >> 1;
    const int* col = sel ? col2 : col1;
    const int rb = sel ? n_nodes : 0;
    int e = bx * 256 + threadIdx.x;
    if (e < num_e) atomicAdd(&cnt[rb + col[e]], 1);
}

__global__ __launch_bounds__(256) void scan1_kernel(const int* __restrict__ cnt,
                                                    int* __restrict__ partial, int n)
{
    __shared__ int wsum[4];
    int t = threadIdx.x;
    int i0 = blockIdx.x * 512 + 2 * t;
    int s = ((i0 < n) ? cnt[i0] : 0) + ((i0 + 1 < n) ? cnt[i0 + 1] : 0);
    #pragma unroll
    for (int o = 32; o; o >>= 1) s += __shfl_xor(s, o, 64);
    if ((t & 63) == 0) wsum[t >> 6] = s;
    __syncthreads();
    if (t == 0) partial[blockIdx.x] = wsum[0] + wsum[1] + wsum[2] + wsum[3];
}

__global__ void scan2_kernel(const int* __restrict__ partial, int* __restrict__ pp,
                             int* __restrict__ off, int nch, int noff)
{
    int lane = threadIdx.x;   // 64 threads
    int running = 0;
    for (int base = 0; base < nch; base += 64) {
        int i = base + lane;
        int o = (i < nch) ? partial[i] : 0;
        int v = o;
        #pragma unroll
        for (int d = 1; d < 64; d <<= 1) {
            int u = __shfl_up(v, d, 64);
            if (lane >= d) v += u;
        }
        if (i < nch) pp[i] = running + v - o;
        running += __shfl(v, 63, 64);
    }
    if (lane == 0) off[noff] = running;
}

__global__ __launch_bounds__(256) void scan3_kernel(const int* __restrict__ cnt,
                                                    const int* __restrict__ pp,
                                                    int* __restrict__ off,
                                                    int* __restrict__ cursor, int n)
{
    __shared__ int tmp[256];
    int t = threadIdx.x;
    int i0 = blockIdx.x * 512 + 2 * t;
    int v0 = (i0 < n) ? cnt[i0] : 0;
    int v1 = (i0 + 1 < n) ? cnt[i0 + 1] : 0;
    int pair = v0 + v1;
    tmp[t] = pair;
    __syncthreads();
    for (int d = 1; d < 256; d <<= 1) {
        int x = (t >= d) ? tmp[t - d] : 0;
        __syncthreads();
        tmp[t] += x;
        __syncthreads();
    }
    int excl = tmp[t] - pair + pp[blockIdx.x];
    if (i0 < n)     { off[i0] = excl;          cursor[i0] = excl; }
    if (i0 + 1 < n) { off[i0 + 1] = excl + v0; cursor[i0 + 1] = excl + v0; }
}

// ---------------- fused edge scores + scatter, MFMA MLP, deep prefetch ------------------
// Per wave: 128 edges (8 tiles of 16). ALL memory is issued in the prologue:
// 8 A-fragments (coalesced ea), col/row metadata, sq/sk gathers, and all 8
// atomicAdd slot reservations (CSR in-bucket order is semantically irrelevant).
// The compute sweep then runs MFMA -> tanh -> butterfly -> exp -> store with no
// long-latency op on the critical path.
// 48B CSR record per edge: {src, ex0, ex1, pad, ea[16] bf16}
__global__ __launch_bounds__(256) void edge_score_scatter_kernel(
    const void* __restrict__ ea1p, const void* __restrict__ ea2p,
    const unsigned short* __restrict__ wet,
    const int* __restrict__ row1, const int* __restrict__ col1,
    const int* __restrict__ row2, const int* __restrict__ col2,
    const float* __restrict__ sq_bp, const float* __restrict__ sk_ap,
    const float* __restrict__ sq_ap, const float* __restrict__ sk_bp,
    const float* __restrict__ cvals, const void* __restrict__ a_attn,
    const int* __restrict__ flagp, int* __restrict__ cursor,
    uint4* __restrict__ payload, int n_nodes, int num_e)
{
    const int f32 = *flagp;
    const int sel = blockIdx.x & 1;
    const int bx  = blockIdx.x >> 1;
    const void* ea = sel ? ea2p : ea1p;
    const int* row = sel ? row2 : row1;
    const int* col = sel ? col2 : col1;
    const float* sq_dst = sel ? sq_ap : sq_bp;
    const float* sk_src = sel ? sk_bp : sk_ap;
    const int rb = sel ? n_nodes : 0;

    const int lane = threadIdx.x & 63;
    const int wv   = threadIdx.x >> 6;
    const int ml   = lane & 15;
    const int g    = lane >> 4;
    const int rsel = lane & 3;

    const int base = bx * 512 + wv * 128;
    if (base >= num_e) return;                        // uniform per wave

    const short8 zero8 = {0, 0, 0, 0, 0, 0, 0, 0};

    // B-fragments: B[k][n=t*16+ml], k = g*8..g*8+7 (<16 real, else 0)
    short8 B[4];
    #pragma unroll
    for (int t = 0; t < 4; ++t)
        B[t] = (g < 2) ? __builtin_bit_cast(short8, *(const uint4*)(wet + (t * 16 + ml) * 16 + g * 8))
                       : zero8;
    float av[4];
    #pragma unroll
    for (int t = 0; t < 4; ++t) av[t] = ldf(a_attn, 96 + ((t * 16 + ml) & 31), f32);
    const float c0 = cvals[sel * 2 + 0];
    const float c1 = cvals[sel * 2 + 1];

    // ---- prologue 1: A-fragments for all 8 tiles (coalesced ea stream) ----
    short8 A[8];
    #pragma unroll
    for (int it = 0; it < 8; ++it) {
        int ec = base + it * 16 + ml; if (ec > num_e - 1) ec = num_e - 1;
        if (g < 2) {
            if (f32) {
                const float4* p = (const float4*)((const float*)ea + (size_t)ec * 16 + g * 8);
                float4 f0 = p[0], f1 = p[1];
                short8 a;
                a[0] = (short)f2bf_bits(f0.x); a[1] = (short)f2bf_bits(f0.y);
                a[2] = (short)f2bf_bits(f0.z); a[3] = (short)f2bf_bits(f0.w);
                a[4] = (short)f2bf_bits(f1.x); a[5] = (short)f2bf_bits(f1.y);
                a[6] = (short)f2bf_bits(f1.z); a[7] = (short)f2bf_bits(f1.w);
                A[it] = a;
            } else {
                A[it] = __builtin_bit_cast(short8, *(const uint4*)((const bf16*)ea + (size_t)ec * 16 + g * 8));
            }
        } else {
            A[it] = zero8;
        }
    }

    // ---- prologue 2: metadata + slot reservations (finalize lanes ml<4) ----
    // finalize lane (g, rsel) handles edge it*16 + g*4 + rsel of each tile.
    int ppos[8]; unsigned psrc[8]; float2 psq[8], psk[8];
    #pragma unroll
    for (int it = 0; it < 8; ++it) {
        ppos[it] = 0; psrc[it] = 0;
        psq[it] = make_float2(0.f, 0.f); psk[it] = make_float2(0.f, 0.f);
    }
    if (ml < 4) {
        int pcol[8];
        #pragma unroll
        for (int it = 0; it < 8; ++it) {
            int e = base + it * 16 + g * 4 + rsel;
            int ec = (e < num_e) ? e : (num_e - 1);
            pcol[it] = col[ec];
            psrc[it] = (unsigned)row[ec];
        }
        #pragma unroll
        for (int it = 0; it < 8; ++it) {
            psq[it] = ((const float2*)sq_dst)[pcol[it]];
            psk[it] = ((const float2*)sk_src)[psrc[it]];
        }
        #pragma unroll
        for (int it = 0; it < 8; ++it) {
            int e = base + it * 16 + g * 4 + rsel;
            ppos[it] = (e < num_e) ? atomicAdd(&cursor[rb + pcol[it]], 1) : 0;
        }
    }

    // ---- compute sweep: no long-latency op on the critical path ----
    #pragma unroll
    for (int it = 0; it < 8; ++it) {
        const int e0 = base + it * 16;
        if (e0 < num_e) {
            float4v z = {0.f, 0.f, 0.f, 0.f};
            float4v acc0 = z, acc1 = z, acc2 = z, acc3 = z;
            acc0 = __builtin_amdgcn_mfma_f32_16x16x32_bf16(A[it], B[0], acc0, 0, 0, 0);
            acc1 = __builtin_amdgcn_mfma_f32_16x16x32_bf16(A[it], B[1], acc1, 0, 0, 0);
            acc2 = __builtin_amdgcn_mfma_f32_16x16x32_bf16(A[it], B[2], acc2, 0, 0, 0);
            acc3 = __builtin_amdgcn_mfma_f32_16x16x32_bf16(A[it], B[3], acc3, 0, 0, 0);

            // per-lane partials: s0/s1[r] for edges g*4+r, heads 0/1
            float s0[4], s1[4];
            #pragma unroll
            for (int r = 0; r < 4; ++r) {
                s0[r] = fast_tanh(acc0[r]) * av[0] + fast_tanh(acc1[r]) * av[1];
                s1[r] = fast_tanh(acc2[r]) * av[2] + fast_tanh(acc3[r]) * av[3];
            }
            // butterfly over the 16-lane column group
            #pragma unroll
            for (int o = 1; o < 16; o <<= 1) {
                #pragma unroll
                for (int r = 0; r < 4; ++r) {
                    s0[r] += __shfl_xor(s0[r], o, 64);
                    s1[r] += __shfl_xor(s1[r], o, 64);
                }
            }

            const bool fin = (ml < 4) && (e0 + g * 4 + rsel < num_e);
            if (fin) {
                float a0 = (rsel == 0) ? s0[0] : (rsel == 1) ? s0[1] : (rsel == 2) ? s0[2] : s0[3];
                float a1 = (rsel == 0) ? s1[0] : (rsel == 1) ? s1[1] : (rsel == 2) ? s1[2] : s1[3];
                float v0 = fminf(30.f, fmaxf(-30.f, a0 + psq[it].x + psk[it].x + c0));
                float v1 = fminf(30.f, fmaxf(-30.f, a1 + psq[it].y + psk[it].y + c1));
                uint4* rec = payload + (size_t)3 * ppos[it];
                rec[0] = make_uint4(psrc[it], __float_as_uint(__expf(v0)),
                                    __float_as_uint(__expf(v1)), 0u);
            }
            // writer lane l (<32) targets edge ml=l&15; its finalize lane is
            // ((ml>>2)*16 + (ml&3)) = ((l&12)<<2) | (l&3)
            const int srcl = ((lane & 12) << 2) | (lane & 3);
            const int posx = __shfl(ppos[it], srcl, 64);
            if (lane < 32 && (e0 + ml < num_e)) {
                uint4* rec = payload + (size_t)3 * posx;
                rec[1 + g] = __builtin_bit_cast(uint4, A[it]);   // ea bf16 halves
            }
        }
    }
}

// ---------------- fused aggregation + output projection (both relations, XCD-split) -----
__global__ __launch_bounds__(256) void agg_final_kernel(
    const uint4* __restrict__ payload, const int* __restrict__ off,
    const unsigned short* __restrict__ v_a, const unsigned short* __restrict__ v_b,
    const float* __restrict__ r_a, const float* __restrict__ r_b,
    const void* __restrict__ Wo_a, const void* __restrict__ Wo_b,
    const void* __restrict__ bo_a, const void* __restrict__ bo_b,
    const float* __restrict__ M1, const float* __restrict__ M2,
    const float* __restrict__ c321, const float* __restrict__ c322,
    const int* __restrict__ flagp, void* __restrict__ out,
    int n_nodes, int nbh)
{
    const int sel = blockIdx.x & 1;                 // 0: rel1 (dst=b), 1: rel2 (dst=a)
    const int bx  = blockIdx.x >> 1;
    const unsigned short* v_src = sel ? v_b : v_a;
    const float* r_src = sel ? r_a : r_b;           // residual of DST type
    const void*  Wo    = sel ? Wo_a : Wo_b;
    const void*  bo    = sel ? bo_a : bo_b;
    const float* M     = sel ? M2 : M1;
    const float* c32   = sel ? c322 : c321;
    const int relbase  = sel ? n_nodes : 0;
    const size_t out_off = sel ? 0 : (size_t)n_nodes * 32;

    const int f32  = *flagp;
    const int lane = threadIdx.x & 63;
    const int wv   = threadIdx.x >> 6;
    const int j    = lane & 31;
    const int half = lane >> 5;
    const int c16  = lane & 15;
    const bool hi  = (lane >= 32);

    __shared__ float stage[4][96];   // per-wave: y[64] | u[32]

    float WoR[32], MR[16];
    const int cb = half * 32;
    #pragma unroll
    for (int cc = 0; cc < 32; ++cc)
        WoR[cc] = ldf(Wo, (size_t)(cb + cc) * 32 + j, f32);
    const int ub = half * 16;
    #pragma unroll
    for (int cc = 0; cc < 16; ++cc) MR[cc] = M[(ub + cc) * 32 + j];
    const float boR  = ldf(bo, j, f32);
    const float c32R = c32[j];

    const int stride = nbh * 4;
    const int iters  = (n_nodes + stride - 1) / stride;
    int d = bx * 4 + wv;

    for (int it = 0; it < iters; ++it, d += stride) {
        const bool valid = (d < n_nodes);
        const int dd  = valid ? d : (n_nodes - 1);
        const int idx = relbase + dd;
        const int b   = __builtin_amdgcn_readfirstlane(off[idx]);
        const int en  = __builtin_amdgcn_readfirstlane(off[idx + 1]);
        const int deg = en - b;

        const float rv = r_src[(size_t)dd * 32 + j];   // early: overlaps edge loop

        float den0 = 0.f, den1 = 0.f, y = 0.f, ua = 0.f;
        int k = b;
        #pragma unroll 1
        for (; k + 8 <= en; k += 8) {
            uint4 m[8];
            #pragma unroll
            for (int q = 0; q < 8; ++q) m[q] = payload[(size_t)3 * (k + q)];
            float ev[8];
            #pragma unroll
            for (int q = 0; q < 8; ++q) {
                const unsigned short* pq = (const unsigned short*)(payload + (size_t)3 * (k + q) + 1);
                ev[q] = __uint_as_float((unsigned)pq[c16] << 16);
            }
            float vv[8];
            #pragma unroll
            for (int q = 0; q < 8; ++q)
                vv[q] = __uint_as_float((unsigned)v_src[(size_t)m[q].x * 64 + lane] << 16);
            #pragma unroll
            for (int q = 0; q < 8; ++q) {
                float e0 = __uint_as_float(m[q].y), e1 = __uint_as_float(m[q].z);
                den0 += e0; den1 += e1;
                float xw = hi ? e1 : e0;
                y  = fmaf(xw, vv[q], y);
                ua = fmaf(xw, ev[q], ua);
            }
        }
        #pragma unroll 1
        for (; k < en; ++k) {
            uint4 mm = payload[(size_t)3 * k];
            const unsigned short* pq = (const unsigned short*)(payload + (size_t)3 * k + 1);
            float evs = __uint_as_float((unsigned)pq[c16] << 16);
            float vvs = __uint_as_float((unsigned)v_src[(size_t)mm.x * 64 + lane] << 16);
            float e0 = __uint_as_float(mm.y), e1 = __uint_as_float(mm.z);
            den0 += e0; den1 += e1;
            float xw = hi ? e1 : e0;
            y  = fmaf(xw, vvs, y);
            ua = fmaf(xw, evs, ua);
        }

        float inv0 = (deg > 0) ? __builtin_amdgcn_rcpf(den0) : 0.f;
        float inv1 = (deg > 0) ? __builtin_amdgcn_rcpf(den1) : 0.f;
        const float invh = hi ? inv1 : inv0;
        y  *= invh;
        ua *= invh;

        // wave-private LDS staging (lockstep wave64 + lgkmcnt drain).
        float* st = stage[wv];
        st[lane] = y;
        if ((lane & 31) < 16) st[64 + half * 16 + c16] = ua;
        __asm__ volatile("s_waitcnt lgkmcnt(0)" ::: "memory");

        float acc = 0.f;
        #pragma unroll
        for (int cc = 0; cc < 32; ++cc)
            acc = fmaf(st[cb + cc], WoR[cc], acc);
        #pragma unroll
        for (int cc = 0; cc < 16; ++cc)
            acc = fmaf(st[64 + ub + cc], MR[cc], acc);

        float other = __shfl(acc, lane ^ 32, 64);
        if (valid && lane < 32) {
            float o = acc + other + boR + rv + ((deg > 0) ? c32R : 0.f);
            stf(out, out_off + (size_t)dd * 32 + j, f32, o);
        }
        __asm__ volatile("" ::: "memory");
        __builtin_amdgcn_wave_barrier();
    }
}

extern "C" void kernel_launch(void* const* d_in, const int* in_sizes, int n_in,
                              void* d_out, int out_size, void* d_ws, size_t ws_size,
                              hipStream_t stream)
{
    const void* x_a   = d_in[0];
    const void* x_b   = d_in[1];
    const void* ea1   = d_in[2];
    const void* ea2   = d_in[3];
    const void* Wq_a  = d_in[4];
    const void* Wk_a  = d_in[5];
    const void* Wv_a  = d_in[6];
    const void* Wq_b  = d_in[7];
    const void* Wk_b  = d_in[8];
    const void* Wv_b  = d_in[9];
    const void* emb_a = d_in[10];
    const void* emb_b = d_in[11];
    const void* rel1  = d_in[12];
    const void* rel2  = d_in[13];
    const void* We    = d_in[14];
    const void* a_at  = d_in[15];
    const void* Wo_a  = d_in[16];
    const void* bo_a  = d_in[17];
    const void* Wo_b  = d_in[18];
    const void* bo_b  = d_in[19];
    const void* Wr_a  = d_in[20];
    const void* Wr_b  = d_in[21];
    const int*  row1  = (const int*)d_in[22];
    const int*  col1  = (const int*)d_in[23];
    const int*  row2  = (const int*)d_in[24];
    const int*  col2  = (const int*)d_in[25];

    const int N = in_sizes[0] / 64;   // nodes per type
    const int E = in_sizes[22];       // edges per relation

    // ---- workspace layout (float units) ----
    float* ws = (float*)d_ws;
    size_t off = 0;
    int*   flag = (int*)ws;        off += 64;
    unsigned short* v_a = (unsigned short*)(ws + off); off += (size_t)N * 32;  // bf16 N x 64
    unsigned short* v_b = (unsigned short*)(ws + off); off += (size_t)N * 32;
    float* r_a  = ws + off;        off += (size_t)N * 32;
    float* r_b  = ws + off;        off += (size_t)N * 32;
    float* sq_a = ws + off;        off += (size_t)N * 2;
    float* sk_a = ws + off;        off += (size_t)N * 2;
    float* sq_b = ws + off;        off += (size_t)N * 2;
    float* sk_b = ws + off;        off += (size_t)N * 2;
    float* cvals = ws + off;       off += 4;
    off = (off + 3) & ~(size_t)3;  // 16B align
    unsigned short* wt = (unsigned short*)(ws + off); off += 29696 / 2;  // 6x4096+2x2048+1024 bf16
    float* M1   = ws + off;        off += 1024;
    float* c321 = ws + off;        off += 32;
    float* M2   = ws + off;        off += 1024;
    float* c322 = ws + off;        off += 32;
    int*   cnt    = (int*)(ws + off);  off += (size_t)2 * N;
    int*   offs   = (int*)(ws + off);  off += (size_t)2 * N + 2;
    int*   cursor = (int*)(ws + off);  off += (size_t)2 * N;
    int*   partial = (int*)(ws + off); off += 512;
    int*   pp      = (int*)(ws + off); off += 512;
    off = (off + 3) & ~(size_t)3;     // 16B align for uint4
    uint4* payload = (uint4*)(ws + off); off += (size_t)2 * E * 12;  // 48B records

    const int tiles        = (N + 15) >> 4;
    const int mfma_blocks  = (2 * tiles + 3) / 4;
    const int score_blocks = (E + 511) / 512;
    const int eb_blocks    = (E + 255) / 256;
    const int nch          = (2 * N + 511) / 512;
    const int agg_half     = 2048;                      // blocks per relation

    detect_kernel<<<1, 128, 0, stream>>>((const unsigned short*)a_at, flag);
    hipMemsetAsync(cnt, 0, (size_t)2 * N * sizeof(int), stream);

    prep_small_kernel<<<11, 256, 0, stream>>>(
        Wq_a, Wk_a, Wv_a, Wq_b, Wk_b, Wv_b, Wr_a, Wr_b,
        We, Wo_a, Wo_b, rel1, rel2, a_at, flag,
        wt, M1, c321, M2, c322, cvals);

    node_prep_mfma_kernel<<<mfma_blocks, 256, 0, stream>>>(
        x_a, x_b, wt, emb_a, emb_b, a_at, flag,
        v_a, v_b, r_a, r_b, sq_a, sk_a, sq_b, sk_b, N, tiles);

    hist_kernel<<<2 * eb_blocks, 256, 0, stream>>>(col1, col2, cnt, N, E);
    scan1_kernel<<<nch, 256, 0, stream>>>(cnt, partial, 2 * N);
    scan2_kernel<<<1, 64, 0, stream>>>(partial, pp, offs, nch, 2 * N);
    scan3_kernel<<<nch, 256, 0, stream>>>(cnt, pp, offs, cursor, 2 * N);

    edge_score_scatter_kernel<<<2 * score_blocks, 256, 0, stream>>>(
        ea1, ea2, wt + 28672, row1, col1, row2, col2,
        sq_b, sk_a, sq_a, sk_b, cvals, a_at, flag,
        cursor, payload, N, E);

    agg_final_kernel<<<2 * agg_half, 256, 0, stream>>>(
        payload, offs, v_a, v_b, r_a, r_b, Wo_a, Wo_b, bo_a, bo_b,
        M1, M2, c321, c322, flag, d_out, N, agg_half);
}

// Round 5
// 525.320 us; speedup vs baseline: 1.0590x; 1.0319x over previous
//
#include <hip/hip_runtime.h>
#include <hip/hip_bf16.h>

typedef __hip_bfloat16 bf16;
typedef __attribute__((ext_vector_type(8))) short short8;
typedef __attribute__((ext_vector_type(4))) float float4v;

static __device__ __forceinline__ float b2f(bf16 x) { return __bfloat162float(x); }

// dtype-dispatched load/store: f32=1 -> buffer is float32, f32=0 -> bfloat16.
static __device__ __forceinline__ float ldf(const void* p, size_t i, int f32) {
    return f32 ? ((const float*)p)[i] : b2f(((const bf16*)p)[i]);
}
static __device__ __forceinline__ void stf(void* p, size_t i, int f32, float v) {
    if (f32) ((float*)p)[i] = v;
    else     ((bf16*)p)[i] = __float2bfloat16(v);
}
static __device__ __forceinline__ unsigned short f2bf_bits(float f) {
    bf16 h = __float2bfloat16(f);
    return *(unsigned short*)&h;
}

// fast tanh: 1 - 2/(e^2x + 1)
static __device__ __forceinline__ float fast_tanh(float x) {
    float t = __expf(2.f * x);
    return 1.f - 2.f * __builtin_amdgcn_rcpf(t + 1.f);
}

// ---------------- dtype detector ----------------
__global__ void detect_kernel(const unsigned short* __restrict__ a, int* __restrict__ flag)
{
    __shared__ int cnt;
    if (threadIdx.x == 0) cnt = 0;
    __syncthreads();
    unsigned e = (a[threadIdx.x] >> 7) & 0xFF;
    if (e < 100 || e > 133) atomicAdd(&cnt, 1);
    __syncthreads();
    if (threadIdx.x == 0) *flag = (cnt >= 16) ? 1 : 0;   // 1 => float32 tensors
}

// ---------------- small prep: W transposes + M/c32/cvals + We^T precompute --------------
// blocks 0..5: 64x64 W transpose; 6..7: 64x32 Wr transpose; 8..9: per-relation precompute
// block 10: wet[n*16+k] = bf16(We[k*64+n])  (64x16, for the edge-MLP MFMA B-fragments)
__global__ __launch_bounds__(256) void prep_small_kernel(
    const void* __restrict__ W0, const void* __restrict__ W1,
    const void* __restrict__ W2, const void* __restrict__ W3,
    const void* __restrict__ W4, const void* __restrict__ W5,
    const void* __restrict__ Wr_a, const void* __restrict__ Wr_b,
    const void* __restrict__ We,
    const void* __restrict__ Wo_a, const void* __restrict__ Wo_b,
    const void* __restrict__ rel1, const void* __restrict__ rel2,
    const void* __restrict__ a_attn, const int* __restrict__ flagp,
    unsigned short* __restrict__ wt,
    float* __restrict__ M1, float* __restrict__ c321,
    float* __restrict__ M2, float* __restrict__ c322,
    float* __restrict__ cvals)
{
    const int f32 = *flagp;
    const int bid = blockIdx.x;
    if (bid < 6) {
        const void* src;
        switch (bid) {
            case 0: src = W0; break; case 1: src = W1; break; case 2: src = W2; break;
            case 3: src = W3; break; case 4: src = W4; break; default: src = W5; break;
        }
        unsigned short* dst = wt + bid * 4096;
        for (int i = threadIdx.x; i < 4096; i += 256) {
            int c = i >> 6, j = i & 63;
            dst[j * 64 + c] = f2bf_bits(ldf(src, c * 64 + j, f32));
        }
    } else if (bid < 8) {
        const void* src = (bid == 6) ? Wr_a : Wr_b;
        unsigned short* dst = wt + 24576 + (bid - 6) * 2048;
        for (int i = threadIdx.x; i < 2048; i += 256) {
            int c = i >> 5, j = i & 31;          // c: 64 in-rows, j: 32 out-cols
            dst[j * 64 + c] = f2bf_bits(ldf(src, c * 32 + j, f32));
        }
    } else if (bid < 10) {
        const int sel = bid - 8;                 // 0: rel1/Wo_b, 1: rel2/Wo_a
        const void* Wo  = sel ? Wo_a : Wo_b;
        const void* rel = sel ? rel2 : rel1;
        float* M   = sel ? M2 : M1;
        float* c32 = sel ? c322 : c321;
        const int t = threadIdx.x;
        for (int i = t; i < 1024; i += 256) {
            int m = i >> 5, j = i & 31;
            int h = m >> 4, c = m & 15;
            float s = 0.f;
            for (int jj = 0; jj < 32; ++jj)
                s += ldf(We, c * 64 + h * 32 + jj, f32) * ldf(Wo, (size_t)(h * 32 + jj) * 32 + j, f32);
            M[m * 32 + j] = s;
        }
        if (t < 32) {
            float s2 = 0.f;
            for (int ch = 0; ch < 64; ++ch)
                s2 += ldf(rel, ch, f32) * ldf(Wo, (size_t)ch * 32 + t, f32);
            c32[t] = s2;
        }
        if (t == 252 || t == 253) {
            int h = t - 252;
            float s3 = 0.f;
            for (int l = 0; l < 32; ++l)
                s3 += tanhf(ldf(rel, h * 32 + l, f32)) * ldf(a_attn, 64 + l, f32);
            cvals[sel * 2 + h] = s3;
        }
    } else {
        unsigned short* wet = wt + 28672;
        for (int i = threadIdx.x; i < 1024; i += 256) {
            int n = i >> 4, k = i & 15;
            wet[n * 16 + k] = f2bf_bits(ldf(We, k * 64 + n, f32));
        }
    }
}

// ---------------- node prep (MFMA) + fused histogram ----------------
// blocks [0, mfma_blocks): q/k scores, v (bf16), r = x@Wr
// blocks [mfma_blocks, ...): histogram of col1/col2 into cnt (overlaps with MFMA work)
__global__ __launch_bounds__(256) void node_prep_mfma_kernel(
    const void* __restrict__ x_a, const void* __restrict__ x_b,
    const unsigned short* __restrict__ wt,
    const void* __restrict__ emb_a, const void* __restrict__ emb_b,
    const void* __restrict__ a_attn, const int* __restrict__ flagp,
    unsigned short* __restrict__ v_a, unsigned short* __restrict__ v_b,
    float* __restrict__ r_a, float* __restrict__ r_b,
    float* __restrict__ sq_a, float* __restrict__ sk_a,
    float* __restrict__ sq_b, float* __restrict__ sk_b,
    const int* __restrict__ col1, const int* __restrict__ col2,
    int* __restrict__ cnt,
    int n_nodes, int tiles, int mfma_blocks, int num_e)
{
    const int f32 = *flagp;

    if ((int)blockIdx.x >= mfma_blocks) {
        // ---- histogram role ----
        const int hb  = blockIdx.x - mfma_blocks;
        const int sel = hb & 1;
        const int bx  = hb >> 1;
        const int* col = sel ? col2 : col1;
        const int rb = sel ? n_nodes : 0;
        int e = bx * 256 + threadIdx.x;
        if (e < num_e) atomicAdd(&cnt[rb + col[e]], 1);
        return;
    }

    const int wave_id = blockIdx.x * 4 + (threadIdx.x >> 6);
    if (wave_id >= 2 * tiles) return;
    const int type = (wave_id >= tiles);
    const int tile = type ? (wave_id - tiles) : wave_id;

    const void* xp = type ? x_b : x_a;
    const unsigned short* wq = wt + (type ? 3 * 4096 : 0);
    const unsigned short* wk = wq + 4096;
    const unsigned short* wv = wk + 4096;
    const unsigned short* wr = wt + 24576 + (type ? 2048 : 0);
    const void* embp = type ? emb_b : emb_a;
    unsigned short* v_out = type ? v_b : v_a;
    float*  r_out  = type ? r_b : r_a;
    float2* sq_out = (float2*)(type ? sq_b : sq_a);
    float2* sk_out = (float2*)(type ? sk_b : sk_a);

    const int lane = threadIdx.x & 63;
    const int ml   = lane & 15;        // node-row (A) / out-col (B,D)
    const int g    = lane >> 4;        // quad
    const int g8   = g * 8;

    float embc[4], acq[4], ack[4];
    #pragma unroll
    for (int t = 0; t < 4; ++t) {
        int colt = t * 16 + ml;
        embc[t] = ldf(embp, colt, f32);
        acq[t]  = ldf(a_attn, colt & 31, f32);
        ack[t]  = ldf(a_attn, 32 + (colt & 31), f32);
    }

    short8 Bq[4][2], Bk[4][2], Bv[4][2], Br[2][2];
    #pragma unroll
    for (int t = 0; t < 4; ++t) {
        const int rowo = (t * 16 + ml) * 64;
        #pragma unroll
        for (int kh = 0; kh < 2; ++kh) {
            const int o = rowo + kh * 32 + g8;
            Bq[t][kh] = __builtin_bit_cast(short8, *(const uint4*)(wq + o));
            Bk[t][kh] = __builtin_bit_cast(short8, *(const uint4*)(wk + o));
            Bv[t][kh] = __builtin_bit_cast(short8, *(const uint4*)(wv + o));
            if (t < 2)
                Br[t][kh] = __builtin_bit_cast(short8, *(const uint4*)(wr + o));
        }
    }

    const int n0 = tile << 4;
    int nr = n0 + ml; if (nr > n_nodes - 1) nr = n_nodes - 1;
    short8 A0, A1;
    if (f32) {
        const float4* xr = (const float4*)((const float*)xp + (size_t)nr * 64);
        float4 f0 = xr[2*g], f1 = xr[2*g+1], f2 = xr[8+2*g], f3 = xr[9+2*g];
        short8 a0, a1;
        a0[0]=(short)f2bf_bits(f0.x); a0[1]=(short)f2bf_bits(f0.y);
        a0[2]=(short)f2bf_bits(f0.z); a0[3]=(short)f2bf_bits(f0.w);
        a0[4]=(short)f2bf_bits(f1.x); a0[5]=(short)f2bf_bits(f1.y);
        a0[6]=(short)f2bf_bits(f1.z); a0[7]=(short)f2bf_bits(f1.w);
        a1[0]=(short)f2bf_bits(f2.x); a1[1]=(short)f2bf_bits(f2.y);
        a1[2]=(short)f2bf_bits(f2.z); a1[3]=(short)f2bf_bits(f2.w);
        a1[4]=(short)f2bf_bits(f3.x); a1[5]=(short)f2bf_bits(f3.y);
        a1[6]=(short)f2bf_bits(f3.z); a1[7]=(short)f2bf_bits(f3.w);
        A0 = a0; A1 = a1;
    } else {
        const uint4* xr = (const uint4*)((const bf16*)xp + (size_t)nr * 64);
        A0 = __builtin_bit_cast(short8, xr[g]);
        A1 = __builtin_bit_cast(short8, xr[4 + g]);
    }

    float4v accq[4], acck[4], accv[4], accr[2];
    #pragma unroll
    for (int t = 0; t < 4; ++t) {
        float4v z = {0.f, 0.f, 0.f, 0.f};
        accq[t] = z; acck[t] = z; accv[t] = z;
        if (t < 2) accr[t] = z;
    }
    #pragma unroll
    for (int t = 0; t < 4; ++t) {
        accq[t] = __builtin_amdgcn_mfma_f32_16x16x32_bf16(A0, Bq[t][0], accq[t], 0, 0, 0);
        accq[t] = __builtin_amdgcn_mfma_f32_16x16x32_bf16(A1, Bq[t][1], accq[t], 0, 0, 0);
        acck[t] = __builtin_amdgcn_mfma_f32_16x16x32_bf16(A0, Bk[t][0], acck[t], 0, 0, 0);
        acck[t] = __builtin_amdgcn_mfma_f32_16x16x32_bf16(A1, Bk[t][1], acck[t], 0, 0, 0);
        accv[t] = __builtin_amdgcn_mfma_f32_16x16x32_bf16(A0, Bv[t][0], accv[t], 0, 0, 0);
        accv[t] = __builtin_amdgcn_mfma_f32_16x16x32_bf16(A1, Bv[t][1], accv[t], 0, 0, 0);
        if (t < 2) {
            accr[t] = __builtin_amdgcn_mfma_f32_16x16x32_bf16(A0, Br[t][0], accr[t], 0, 0, 0);
            accr[t] = __builtin_amdgcn_mfma_f32_16x16x32_bf16(A1, Br[t][1], accr[t], 0, 0, 0);
        }
    }

    #pragma unroll
    for (int t = 0; t < 4; ++t) {
        #pragma unroll
        for (int r = 0; r < 4; ++r) {
            int node = n0 + g * 4 + r;
            if (node < n_nodes) {
                v_out[(size_t)node * 64 + t * 16 + ml] = f2bf_bits(accv[t][r]);
                if (t < 2) r_out[(size_t)node * 32 + t * 16 + ml] = accr[t][r];
            }
        }
    }

    #pragma unroll
    for (int r = 0; r < 4; ++r) {
        float q0 = fast_tanh(accq[0][r] + embc[0]) * acq[0]
                 + fast_tanh(accq[1][r] + embc[1]) * acq[1];
        float q1 = fast_tanh(accq[2][r] + embc[2]) * acq[2]
                 + fast_tanh(accq[3][r] + embc[3]) * acq[3];
        float k0 = fast_tanh(acck[0][r] + embc[0]) * ack[0]
                 + fast_tanh(acck[1][r] + embc[1]) * ack[1];
        float k1 = fast_tanh(acck[2][r] + embc[2]) * ack[2]
                 + fast_tanh(acck[3][r] + embc[3]) * ack[3];
        #pragma unroll
        for (int o = 1; o < 16; o <<= 1) {
            q0 += __shfl_xor(q0, o, 64); q1 += __shfl_xor(q1, o, 64);
            k0 += __shfl_xor(k0, o, 64); k1 += __shfl_xor(k1, o, 64);
        }
        int node = n0 + g * 4 + r;
        if (ml == 0 && node < n_nodes) {
            sq_out[node] = make_float2(q0, q1);
            sk_out[node] = make_float2(k0, k1);
        }
    }
}

// ---------------- scans (CSR offsets) ----------------
__global__ __launch_bounds__(256) void scan1_kernel(const int* __restrict__ cnt,
                                                    int* __restrict__ partial, int n)
{
    __shared__ int wsum[4];
    int t = threadIdx.x;
    int i0 = blockIdx.x * 512 + 2 * t;
    int s = ((i0 < n) ? cnt[i0] : 0) + ((i0 + 1 < n) ? cnt[i0 + 1] : 0);
    #pragma unroll
    for (int o = 32; o; o >>= 1) s += __shfl_xor(s, o, 64);
    if ((t & 63) == 0) wsum[t >> 6] = s;
    __syncthreads();
    if (t == 0) partial[blockIdx.x] = wsum[0] + wsum[1] + wsum[2] + wsum[3];
}

__global__ void scan2_kernel(const int* __restrict__ partial, int* __restrict__ pp,
                             int* __restrict__ off, int nch, int noff)
{
    int lane = threadIdx.x;   // 64 threads
    int running = 0;
    for (int base = 0; base < nch; base += 64) {
        int i = base + lane;
        int o = (i < nch) ? partial[i] : 0;
        int v = o;
        #pragma unroll
        for (int d = 1; d < 64; d <<= 1) {
            int u = __shfl_up(v, d, 64);
            if (lane >= d) v += u;
        }
        if (i < nch) pp[i] = running + v - o;
        running += __shfl(v, 63, 64);
    }
    if (lane == 0) off[noff] = running;
}

__global__ __launch_bounds__(256) void scan3_kernel(const int* __restrict__ cnt,
                                                    const int* __restrict__ pp,
                                                    int* __restrict__ off,
                                                    int* __restrict__ cursor, int n)
{
    __shared__ int tmp[256];
    int t = threadIdx.x;
    int i0 = blockIdx.x * 512 + 2 * t;
    int v0 = (i0 < n) ? cnt[i0] : 0;
    int v1 = (i0 + 1 < n) ? cnt[i0 + 1] : 0;
    int pair = v0 + v1;
    tmp[t] = pair;
    __syncthreads();
    for (int d = 1; d < 256; d <<= 1) {
        int x = (t >= d) ? tmp[t - d] : 0;
        __syncthreads();
        tmp[t] += x;
        __syncthreads();
    }
    int excl = tmp[t] - pair + pp[blockIdx.x];
    if (i0 < n)     { off[i0] = excl;          cursor[i0] = excl; }
    if (i0 + 1 < n) { off[i0 + 1] = excl + v0; cursor[i0 + 1] = excl + v0; }
}

// ---------------- fused edge scores + scatter, MFMA MLP, deep prefetch ------------------
// Per wave: 64 edges (4 tiles of 16) -- smaller batch => 2x waves, lower VGPR,
// more prologues in flight to hide gather/atomic/store latency.
// 48B CSR record per edge: {src, ex0, ex1, pad, ea[16] bf16}
__global__ __launch_bounds__(256) void edge_score_scatter_kernel(
    const void* __restrict__ ea1p, const void* __restrict__ ea2p,
    const unsigned short* __restrict__ wet,
    const int* __restrict__ row1, const int* __restrict__ col1,
    const int* __restrict__ row2, const int* __restrict__ col2,
    const float* __restrict__ sq_bp, const float* __restrict__ sk_ap,
    const float* __restrict__ sq_ap, const float* __restrict__ sk_bp,
    const float* __restrict__ cvals, const void* __restrict__ a_attn,
    const int* __restrict__ flagp, int* __restrict__ cursor,
    uint4* __restrict__ payload, int n_nodes, int num_e)
{
    const int f32 = *flagp;
    const int sel = blockIdx.x & 1;
    const int bx  = blockIdx.x >> 1;
    const void* ea = sel ? ea2p : ea1p;
    const int* row = sel ? row2 : row1;
    const int* col = sel ? col2 : col1;
    const float* sq_dst = sel ? sq_ap : sq_bp;
    const float* sk_src = sel ? sk_bp : sk_ap;
    const int rb = sel ? n_nodes : 0;

    const int lane = threadIdx.x & 63;
    const int wv   = threadIdx.x >> 6;
    const int ml   = lane & 15;
    const int g    = lane >> 4;
    const int rsel = lane & 3;

    const int base = bx * 256 + wv * 64;
    if (base >= num_e) return;                        // uniform per wave

    const short8 zero8 = {0, 0, 0, 0, 0, 0, 0, 0};

    // B-fragments: B[k][n=t*16+ml], k = g*8..g*8+7 (<16 real, else 0)
    short8 B[4];
    #pragma unroll
    for (int t = 0; t < 4; ++t)
        B[t] = (g < 2) ? __builtin_bit_cast(short8, *(const uint4*)(wet + (t * 16 + ml) * 16 + g * 8))
                       : zero8;
    float av[4];
    #pragma unroll
    for (int t = 0; t < 4; ++t) av[t] = ldf(a_attn, 96 + ((t * 16 + ml) & 31), f32);
    const float c0 = cvals[sel * 2 + 0];
    const float c1 = cvals[sel * 2 + 1];

    // ---- prologue 1: A-fragments for all 4 tiles (coalesced ea stream) ----
    short8 A[4];
    #pragma unroll
    for (int it = 0; it < 4; ++it) {
        int ec = base + it * 16 + ml; if (ec > num_e - 1) ec = num_e - 1;
        if (g < 2) {
            if (f32) {
                const float4* p = (const float4*)((const float*)ea + (size_t)ec * 16 + g * 8);
                float4 f0 = p[0], f1 = p[1];
                short8 a;
                a[0] = (short)f2bf_bits(f0.x); a[1] = (short)f2bf_bits(f0.y);
                a[2] = (short)f2bf_bits(f0.z); a[3] = (short)f2bf_bits(f0.w);
                a[4] = (short)f2bf_bits(f1.x); a[5] = (short)f2bf_bits(f1.y);
                a[6] = (short)f2bf_bits(f1.z); a[7] = (short)f2bf_bits(f1.w);
                A[it] = a;
            } else {
                A[it] = __builtin_bit_cast(short8, *(const uint4*)((const bf16*)ea + (size_t)ec * 16 + g * 8));
            }
        } else {
            A[it] = zero8;
        }
    }

    // ---- prologue 2: metadata + slot reservations (finalize lanes ml<4) ----
    // finalize lane (g, rsel) handles edge it*16 + g*4 + rsel of each tile.
    int ppos[4]; unsigned psrc[4]; float2 psq[4], psk[4];
    #pragma unroll
    for (int it = 0; it < 4; ++it) {
        ppos[it] = 0; psrc[it] = 0;
        psq[it] = make_float2(0.f, 0.f); psk[it] = make_float2(0.f, 0.f);
    }
    if (ml < 4) {
        int pcol[4];
        #pragma unroll
        for (int it = 0; it < 4; ++it) {
            int e = base + it * 16 + g * 4 + rsel;
            int ec = (e < num_e) ? e : (num_e - 1);
            pcol[it] = col[ec];
            psrc[it] = (unsigned)row[ec];
        }
        #pragma unroll
        for (int it = 0; it < 4; ++it) {
            psq[it] = ((const float2*)sq_dst)[pcol[it]];
            psk[it] = ((const float2*)sk_src)[psrc[it]];
        }
        #pragma unroll
        for (int it = 0; it < 4; ++it) {
            int e = base + it * 16 + g * 4 + rsel;
            ppos[it] = (e < num_e) ? atomicAdd(&cursor[rb + pcol[it]], 1) : 0;
        }
    }

    // ---- compute sweep: no long-latency op on the critical path ----
    #pragma unroll
    for (int it = 0; it < 4; ++it) {
        const int e0 = base + it * 16;
        if (e0 < num_e) {
            float4v z = {0.f, 0.f, 0.f, 0.f};
            float4v acc0 = z, acc1 = z, acc2 = z, acc3 = z;
            acc0 = __builtin_amdgcn_mfma_f32_16x16x32_bf16(A[it], B[0], acc0, 0, 0, 0);
            acc1 = __builtin_amdgcn_mfma_f32_16x16x32_bf16(A[it], B[1], acc1, 0, 0, 0);
            acc2 = __builtin_amdgcn_mfma_f32_16x16x32_bf16(A[it], B[2], acc2, 0, 0, 0);
            acc3 = __builtin_amdgcn_mfma_f32_16x16x32_bf16(A[it], B[3], acc3, 0, 0, 0);

            // per-lane partials: s0/s1[r] for edges g*4+r, heads 0/1
            float s0[4], s1[4];
            #pragma unroll
            for (int r = 0; r < 4; ++r) {
                s0[r] = fast_tanh(acc0[r]) * av[0] + fast_tanh(acc1[r]) * av[1];
                s1[r] = fast_tanh(acc2[r]) * av[2] + fast_tanh(acc3[r]) * av[3];
            }
            // butterfly over the 16-lane column group
            #pragma unroll
            for (int o = 1; o < 16; o <<= 1) {
                #pragma unroll
                for (int r = 0; r < 4; ++r) {
                    s0[r] += __shfl_xor(s0[r], o, 64);
                    s1[r] += __shfl_xor(s1[r], o, 64);
                }
            }

            const bool fin = (ml < 4) && (e0 + g * 4 + rsel < num_e);
            if (fin) {
                float a0 = (rsel == 0) ? s0[0] : (rsel == 1) ? s0[1] : (rsel == 2) ? s0[2] : s0[3];
                float a1 = (rsel == 0) ? s1[0] : (rsel == 1) ? s1[1] : (rsel == 2) ? s1[2] : s1[3];
                float v0 = fminf(30.f, fmaxf(-30.f, a0 + psq[it].x + psk[it].x + c0));
                float v1 = fminf(30.f, fmaxf(-30.f, a1 + psq[it].y + psk[it].y + c1));
                uint4* rec = payload + (size_t)3 * ppos[it];
                rec[0] = make_uint4(psrc[it], __float_as_uint(__expf(v0)),
                                    __float_as_uint(__expf(v1)), 0u);
            }
            // writer lane l (<32) targets edge ml=l&15; its finalize lane is
            // ((ml>>2)*16 + (ml&3)) = ((l&12)<<2) | (l&3)
            const int srcl = ((lane & 12) << 2) | (lane & 3);
            const int posx = __shfl(ppos[it], srcl, 64);
            if (lane < 32 && (e0 + ml < num_e)) {
                uint4* rec = payload + (size_t)3 * posx;
                rec[1 + g] = __builtin_bit_cast(uint4, A[it]);   // ea bf16 halves
            }
        }
    }
}

// ---------------- fused aggregation + output projection (both relations, XCD-split) -----
__global__ __launch_bounds__(256) void agg_final_kernel(
    const uint4* __restrict__ payload, const int* __restrict__ off,
    const unsigned short* __restrict__ v_a, const unsigned short* __restrict__ v_b,
    const float* __restrict__ r_a, const float* __restrict__ r_b,
    const void* __restrict__ Wo_a, const void* __restrict__ Wo_b,
    const void* __restrict__ bo_a, const void* __restrict__ bo_b,
    const float* __restrict__ M1, const float* __restrict__ M2,
    const float* __restrict__ c321, const float* __restrict__ c322,
    const int* __restrict__ flagp, void* __restrict__ out,
    int n_nodes, int nbh)
{
    const int sel = blockIdx.x & 1;                 // 0: rel1 (dst=b), 1: rel2 (dst=a)
    const int bx  = blockIdx.x >> 1;
    const unsigned short* v_src = sel ? v_b : v_a;
    const float* r_src = sel ? r_a : r_b;           // residual of DST type
    const void*  Wo    = sel ? Wo_a : Wo_b;
    const void*  bo    = sel ? bo_a : bo_b;
    const float* M     = sel ? M2 : M1;
    const float* c32   = sel ? c322 : c321;
    const int relbase  = sel ? n_nodes : 0;
    const size_t out_off = sel ? 0 : (size_t)n_nodes * 32;

    const int f32  = *flagp;
    const int lane = threadIdx.x & 63;
    const int wv   = threadIdx.x >> 6;
    const int j    = lane & 31;
    const int half = lane >> 5;
    const int c16  = lane & 15;
    const bool hi  = (lane >= 32);

    __shared__ float stage[4][96];   // per-wave: y[64] | u[32]

    float WoR[32], MR[16];
    const int cb = half * 32;
    #pragma unroll
    for (int cc = 0; cc < 32; ++cc)
        WoR[cc] = ldf(Wo, (size_t)(cb + cc) * 32 + j, f32);
    const int ub = half * 16;
    #pragma unroll
    for (int cc = 0; cc < 16; ++cc) MR[cc] = M[(ub + cc) * 32 + j];
    const float boR  = ldf(bo, j, f32);
    const float c32R = c32[j];

    const int stride = nbh * 4;
    const int iters  = (n_nodes + stride - 1) / stride;
    int d = bx * 4 + wv;

    // software pipeline: preload iteration 0's offsets + residual
    int dd0 = (d < n_nodes) ? d : (n_nodes - 1);
    int b_c  = off[relbase + dd0];
    int en_c = off[relbase + dd0 + 1];
    float rv_c = r_src[(size_t)dd0 * 32 + j];

    for (int it = 0; it < iters; ++it, d += stride) {
        const bool valid = (d < n_nodes);
        const int dd  = valid ? d : (n_nodes - 1);

        // issue next iteration's loads early (hide under the edge loop)
        int b_n = 0, en_n = 0; float rv_n = 0.f;
        if (it + 1 < iters) {
            int dn  = d + stride;
            int ddn = (dn < n_nodes) ? dn : (n_nodes - 1);
            b_n  = off[relbase + ddn];
            en_n = off[relbase + ddn + 1];
            rv_n = r_src[(size_t)ddn * 32 + j];
        }

        const int b   = __builtin_amdgcn_readfirstlane(b_c);
        const int en  = __builtin_amdgcn_readfirstlane(en_c);
        const int deg = en - b;
        const float rv = rv_c;

        float den0 = 0.f, den1 = 0.f, y = 0.f, ua = 0.f;
        int k = b;
        #pragma unroll 1
        for (; k + 8 <= en; k += 8) {
            uint4 m[8];
            #pragma unroll
            for (int q = 0; q < 8; ++q) m[q] = payload[(size_t)3 * (k + q)];
            float ev[8];
            #pragma unroll
            for (int q = 0; q < 8; ++q) {
                const unsigned short* pq = (const unsigned short*)(payload + (size_t)3 * (k + q) + 1);
                ev[q] = __uint_as_float((unsigned)pq[c16] << 16);
            }
            float vv[8];
            #pragma unroll
            for (int q = 0; q < 8; ++q)
                vv[q] = __uint_as_float((unsigned)v_src[(size_t)m[q].x * 64 + lane] << 16);
            #pragma unroll
            for (int q = 0; q < 8; ++q) {
                float e0 = __uint_as_float(m[q].y), e1 = __uint_as_float(m[q].z);
                den0 += e0; den1 += e1;
                float xw = hi ? e1 : e0;
                y  = fmaf(xw, vv[q], y);
                ua = fmaf(xw, ev[q], ua);
            }
        }
        #pragma unroll 1
        for (; k < en; ++k) {
            uint4 mm = payload[(size_t)3 * k];
            const unsigned short* pq = (const unsigned short*)(payload + (size_t)3 * k + 1);
            float evs = __uint_as_float((unsigned)pq[c16] << 16);
            float vvs = __uint_as_float((unsigned)v_src[(size_t)mm.x * 64 + lane] << 16);
            float e0 = __uint_as_float(mm.y), e1 = __uint_as_float(mm.z);
            den0 += e0; den1 += e1;
            float xw = hi ? e1 : e0;
            y  = fmaf(xw, vvs, y);
            ua = fmaf(xw, evs, ua);
        }

        float inv0 = (deg > 0) ? __builtin_amdgcn_rcpf(den0) : 0.f;
        float inv1 = (deg > 0) ? __builtin_amdgcn_rcpf(den1) : 0.f;
        const float invh = hi ? inv1 : inv0;
        y  *= invh;
        ua *= invh;

        // wave-private LDS staging (lockstep wave64 + lgkmcnt drain).
        float* st = stage[wv];
        st[lane] = y;
        if ((lane & 31) < 16) st[64 + half * 16 + c16] = ua;
        __asm__ volatile("s_waitcnt lgkmcnt(0)" ::: "memory");

        float acc = 0.f;
        #pragma unroll
        for (int cc = 0; cc < 32; ++cc)
            acc = fmaf(st[cb + cc], WoR[cc], acc);
        #pragma unroll
        for (int cc = 0; cc < 16; ++cc)
            acc = fmaf(st[64 + ub + cc], MR[cc], acc);

        float other = __shfl(acc, lane ^ 32, 64);
        if (valid && lane < 32) {
            float o = acc + other + boR + rv + ((deg > 0) ? c32R : 0.f);
            stf(out, out_off + (size_t)dd * 32 + j, f32, o);
        }
        __asm__ volatile("" ::: "memory");
        __builtin_amdgcn_wave_barrier();

        b_c = b_n; en_c = en_n; rv_c = rv_n;
    }
}

extern "C" void kernel_launch(void* const* d_in, const int* in_sizes, int n_in,
                              void* d_out, int out_size, void* d_ws, size_t ws_size,
                              hipStream_t stream)
{
    const void* x_a   = d_in[0];
    const void* x_b   = d_in[1];
    const void* ea1   = d_in[2];
    const void* ea2   = d_in[3];
    const void* Wq_a  = d_in[4];
    const void* Wk_a  = d_in[5];
    const void* Wv_a  = d_in[6];
    const void* Wq_b  = d_in[7];
    const void* Wk_b  = d_in[8];
    const void* Wv_b  = d_in[9];
    const void* emb_a = d_in[10];
    const void* emb_b = d_in[11];
    const void* rel1  = d_in[12];
    const void* rel2  = d_in[13];
    const void* We    = d_in[14];
    const void* a_at  = d_in[15];
    const void* Wo_a  = d_in[16];
    const void* bo_a  = d_in[17];
    const void* Wo_b  = d_in[18];
    const void* bo_b  = d_in[19];
    const void* Wr_a  = d_in[20];
    const void* Wr_b  = d_in[21];
    const int*  row1  = (const int*)d_in[22];
    const int*  col1  = (const int*)d_in[23];
    const int*  row2  = (const int*)d_in[24];
    const int*  col2  = (const int*)d_in[25];

    const int N = in_sizes[0] / 64;   // nodes per type
    const int E = in_sizes[22];       // edges per relation

    // ---- workspace layout (float units) ----
    float* ws = (float*)d_ws;
    size_t off = 0;
    int*   flag = (int*)ws;        off += 64;
    unsigned short* v_a = (unsigned short*)(ws + off); off += (size_t)N * 32;  // bf16 N x 64
    unsigned short* v_b = (unsigned short*)(ws + off); off += (size_t)N * 32;
    float* r_a  = ws + off;        off += (size_t)N * 32;
    float* r_b  = ws + off;        off += (size_t)N * 32;
    float* sq_a = ws + off;        off += (size_t)N * 2;
    float* sk_a = ws + off;        off += (size_t)N * 2;
    float* sq_b = ws + off;        off += (size_t)N * 2;
    float* sk_b = ws + off;        off += (size_t)N * 2;
    float* cvals = ws + off;       off += 4;
    off = (off + 3) & ~(size_t)3;  // 16B align
    unsigned short* wt = (unsigned short*)(ws + off); off += 29696 / 2;  // 6x4096+2x2048+1024 bf16
    float* M1   = ws + off;        off += 1024;
    float* c321 = ws + off;        off += 32;
    float* M2   = ws + off;        off += 1024;
    float* c322 = ws + off;        off += 32;
    int*   cnt    = (int*)(ws + off);  off += (size_t)2 * N;
    int*   offs   = (int*)(ws + off);  off += (size_t)2 * N + 2;
    int*   cursor = (int*)(ws + off);  off += (size_t)2 * N;
    int*   partial = (int*)(ws + off); off += 512;
    int*   pp      = (int*)(ws + off); off += 512;
    off = (off + 3) & ~(size_t)3;     // 16B align for uint4
    uint4* payload = (uint4*)(ws + off); off += (size_t)2 * E * 12;  // 48B records

    const int tiles        = (N + 15) >> 4;
    const int mfma_blocks  = (2 * tiles + 3) / 4;
    const int eb_blocks    = (E + 255) / 256;
    const int score_blocks = (E + 255) / 256;           // 256 edges per block (4 waves x 64)
    const int nch          = (2 * N + 511) / 512;
    const int agg_half     = 2048;                      // blocks per relation

    detect_kernel<<<1, 128, 0, stream>>>((const unsigned short*)a_at, flag);
    hipMemsetAsync(cnt, 0, (size_t)2 * N * sizeof(int), stream);

    prep_small_kernel<<<11, 256, 0, stream>>>(
        Wq_a, Wk_a, Wv_a, Wq_b, Wk_b, Wv_b, Wr_a, Wr_b,
        We, Wo_a, Wo_b, rel1, rel2, a_at, flag,
        wt, M1, c321, M2, c322, cvals);

    // node prep + fused histogram (extra blocks)
    node_prep_mfma_kernel<<<mfma_blocks + 2 * eb_blocks, 256, 0, stream>>>(
        x_a, x_b, wt, emb_a, emb_b, a_at, flag,
        v_a, v_b, r_a, r_b, sq_a, sk_a, sq_b, sk_b,
        col1, col2, cnt, N, tiles, mfma_blocks, E);

    scan1_kernel<<<nch, 256, 0, stream>>>(cnt, partial, 2 * N);
    scan2_kernel<<<1, 64, 0, stream>>>(partial, pp, offs, nch, 2 * N);
    scan3_kernel<<<nch, 256, 0, stream>>>(cnt, pp, offs, cursor, 2 * N);

    edge_score_scatter_kernel<<<2 * score_blocks, 256, 0, stream>>>(
        ea1, ea2, wt + 28672, row1, col1, row2, col2,
        sq_b, sk_a, sq_a, sk_b, cvals, a_at, flag,
        cursor, payload, N, E);

    agg_final_kernel<<<2 * agg_half, 256, 0, stream>>>(
        payload, offs, v_a, v_b, r_a, r_b, Wo_a, Wo_b, bo_a, bo_b,
        M1, M2, c321, c322, flag, d_out, N, agg_half);
}

// Round 6
// 525.273 us; speedup vs baseline: 1.0591x; 1.0001x over previous
//
#include <hip/hip_runtime.h>
#include <hip/hip_bf16.h>

typedef __hip_bfloat16 bf16;
typedef __attribute__((ext_vector_type(8))) short short8;
typedef __attribute__((ext_vector_type(4))) float float4v;

static __device__ __forceinline__ float b2f(bf16 x) { return __bfloat162float(x); }

// dtype-dispatched load/store: f32=1 -> buffer is float32, f32=0 -> bfloat16.
static __device__ __forceinline__ float ldf(const void* p, size_t i, int f32) {
    return f32 ? ((const float*)p)[i] : b2f(((const bf16*)p)[i]);
}
static __device__ __forceinline__ void stf(void* p, size_t i, int f32, float v) {
    if (f32) ((float*)p)[i] = v;
    else     ((bf16*)p)[i] = __float2bfloat16(v);
}
static __device__ __forceinline__ unsigned short f2bf_bits(float f) {
    bf16 h = __float2bfloat16(f);
    return *(unsigned short*)&h;
}

// fast tanh: 1 - 2/(e^2x + 1)
static __device__ __forceinline__ float fast_tanh(float x) {
    float t = __expf(2.f * x);
    return 1.f - 2.f * __builtin_amdgcn_rcpf(t + 1.f);
}

// ---------------- dtype detector ----------------
__global__ void detect_kernel(const unsigned short* __restrict__ a, int* __restrict__ flag)
{
    __shared__ int cnt;
    if (threadIdx.x == 0) cnt = 0;
    __syncthreads();
    unsigned e = (a[threadIdx.x] >> 7) & 0xFF;
    if (e < 100 || e > 133) atomicAdd(&cnt, 1);
    __syncthreads();
    if (threadIdx.x == 0) *flag = (cnt >= 16) ? 1 : 0;   // 1 => float32 tensors
}

// ---------------- small prep: W transposes + M/c32/cvals + We^T precompute --------------
__global__ __launch_bounds__(256) void prep_small_kernel(
    const void* __restrict__ W0, const void* __restrict__ W1,
    const void* __restrict__ W2, const void* __restrict__ W3,
    const void* __restrict__ W4, const void* __restrict__ W5,
    const void* __restrict__ Wr_a, const void* __restrict__ Wr_b,
    const void* __restrict__ We,
    const void* __restrict__ Wo_a, const void* __restrict__ Wo_b,
    const void* __restrict__ rel1, const void* __restrict__ rel2,
    const void* __restrict__ a_attn, const int* __restrict__ flagp,
    unsigned short* __restrict__ wt,
    float* __restrict__ M1, float* __restrict__ c321,
    float* __restrict__ M2, float* __restrict__ c322,
    float* __restrict__ cvals)
{
    const int f32 = *flagp;
    const int bid = blockIdx.x;
    if (bid < 6) {
        const void* src;
        switch (bid) {
            case 0: src = W0; break; case 1: src = W1; break; case 2: src = W2; break;
            case 3: src = W3; break; case 4: src = W4; break; default: src = W5; break;
        }
        unsigned short* dst = wt + bid * 4096;
        for (int i = threadIdx.x; i < 4096; i += 256) {
            int c = i >> 6, j = i & 63;
            dst[j * 64 + c] = f2bf_bits(ldf(src, c * 64 + j, f32));
        }
    } else if (bid < 8) {
        const void* src = (bid == 6) ? Wr_a : Wr_b;
        unsigned short* dst = wt + 24576 + (bid - 6) * 2048;
        for (int i = threadIdx.x; i < 2048; i += 256) {
            int c = i >> 5, j = i & 31;          // c: 64 in-rows, j: 32 out-cols
            dst[j * 64 + c] = f2bf_bits(ldf(src, c * 32 + j, f32));
        }
    } else if (bid < 10) {
        const int sel = bid - 8;                 // 0: rel1/Wo_b, 1: rel2/Wo_a
        const void* Wo  = sel ? Wo_a : Wo_b;
        const void* rel = sel ? rel2 : rel1;
        float* M   = sel ? M2 : M1;
        float* c32 = sel ? c322 : c321;
        const int t = threadIdx.x;
        for (int i = t; i < 1024; i += 256) {
            int m = i >> 5, j = i & 31;
            int h = m >> 4, c = m & 15;
            float s = 0.f;
            for (int jj = 0; jj < 32; ++jj)
                s += ldf(We, c * 64 + h * 32 + jj, f32) * ldf(Wo, (size_t)(h * 32 + jj) * 32 + j, f32);
            M[m * 32 + j] = s;
        }
        if (t < 32) {
            float s2 = 0.f;
            for (int ch = 0; ch < 64; ++ch)
                s2 += ldf(rel, ch, f32) * ldf(Wo, (size_t)ch * 32 + t, f32);
            c32[t] = s2;
        }
        if (t == 252 || t == 253) {
            int h = t - 252;
            float s3 = 0.f;
            for (int l = 0; l < 32; ++l)
                s3 += tanhf(ldf(rel, h * 32 + l, f32)) * ldf(a_attn, 64 + l, f32);
            cvals[sel * 2 + h] = s3;
        }
    } else {
        unsigned short* wet = wt + 28672;
        for (int i = threadIdx.x; i < 1024; i += 256) {
            int n = i >> 4, k = i & 15;
            wet[n * 16 + k] = f2bf_bits(ldf(We, k * 64 + n, f32));
        }
    }
}

// ---------------- node prep (MFMA) + fused histogram w/ rank capture ----------------
// blocks [0, mfma_blocks): q/k scores, v (bf16), r = x@Wr
// blocks [mfma_blocks, ...): histogram; the atomicAdd return IS the in-bucket rank,
// persisted so the edge kernel needs no atomics at all.
__global__ __launch_bounds__(256) void node_prep_mfma_kernel(
    const void* __restrict__ x_a, const void* __restrict__ x_b,
    const unsigned short* __restrict__ wt,
    const void* __restrict__ emb_a, const void* __restrict__ emb_b,
    const void* __restrict__ a_attn, const int* __restrict__ flagp,
    unsigned short* __restrict__ v_a, unsigned short* __restrict__ v_b,
    float* __restrict__ r_a, float* __restrict__ r_b,
    float* __restrict__ sq_a, float* __restrict__ sk_a,
    float* __restrict__ sq_b, float* __restrict__ sk_b,
    const int* __restrict__ col1, const int* __restrict__ col2,
    int* __restrict__ cnt, int* __restrict__ rank_out,
    int n_nodes, int tiles, int mfma_blocks, int num_e)
{
    const int f32 = *flagp;

    if ((int)blockIdx.x >= mfma_blocks) {
        // ---- histogram role: count + capture rank ----
        const int hb  = blockIdx.x - mfma_blocks;
        const int sel = hb & 1;
        const int bx  = hb >> 1;
        const int* col = sel ? col2 : col1;
        const int rb = sel ? n_nodes : 0;
        int e = bx * 256 + threadIdx.x;
        if (e < num_e)
            rank_out[(size_t)sel * num_e + e] = atomicAdd(&cnt[rb + col[e]], 1);
        return;
    }

    const int wave_id = blockIdx.x * 4 + (threadIdx.x >> 6);
    if (wave_id >= 2 * tiles) return;
    const int type = (wave_id >= tiles);
    const int tile = type ? (wave_id - tiles) : wave_id;

    const void* xp = type ? x_b : x_a;
    const unsigned short* wq = wt + (type ? 3 * 4096 : 0);
    const unsigned short* wk = wq + 4096;
    const unsigned short* wv = wk + 4096;
    const unsigned short* wr = wt + 24576 + (type ? 2048 : 0);
    const void* embp = type ? emb_b : emb_a;
    unsigned short* v_out = type ? v_b : v_a;
    float*  r_out  = type ? r_b : r_a;
    float2* sq_out = (float2*)(type ? sq_b : sq_a);
    float2* sk_out = (float2*)(type ? sk_b : sk_a);

    const int lane = threadIdx.x & 63;
    const int ml   = lane & 15;        // node-row (A) / out-col (B,D)
    const int g    = lane >> 4;        // quad
    const int g8   = g * 8;

    float embc[4], acq[4], ack[4];
    #pragma unroll
    for (int t = 0; t < 4; ++t) {
        int colt = t * 16 + ml;
        embc[t] = ldf(embp, colt, f32);
        acq[t]  = ldf(a_attn, colt & 31, f32);
        ack[t]  = ldf(a_attn, 32 + (colt & 31), f32);
    }

    short8 Bq[4][2], Bk[4][2], Bv[4][2], Br[2][2];
    #pragma unroll
    for (int t = 0; t < 4; ++t) {
        const int rowo = (t * 16 + ml) * 64;
        #pragma unroll
        for (int kh = 0; kh < 2; ++kh) {
            const int o = rowo + kh * 32 + g8;
            Bq[t][kh] = __builtin_bit_cast(short8, *(const uint4*)(wq + o));
            Bk[t][kh] = __builtin_bit_cast(short8, *(const uint4*)(wk + o));
            Bv[t][kh] = __builtin_bit_cast(short8, *(const uint4*)(wv + o));
            if (t < 2)
                Br[t][kh] = __builtin_bit_cast(short8, *(const uint4*)(wr + o));
        }
    }

    const int n0 = tile << 4;
    int nr = n0 + ml; if (nr > n_nodes - 1) nr = n_nodes - 1;
    short8 A0, A1;
    if (f32) {
        const float4* xr = (const float4*)((const float*)xp + (size_t)nr * 64);
        float4 f0 = xr[2*g], f1 = xr[2*g+1], f2 = xr[8+2*g], f3 = xr[9+2*g];
        short8 a0, a1;
        a0[0]=(short)f2bf_bits(f0.x); a0[1]=(short)f2bf_bits(f0.y);
        a0[2]=(short)f2bf_bits(f0.z); a0[3]=(short)f2bf_bits(f0.w);
        a0[4]=(short)f2bf_bits(f1.x); a0[5]=(short)f2bf_bits(f1.y);
        a0[6]=(short)f2bf_bits(f1.z); a0[7]=(short)f2bf_bits(f1.w);
        a1[0]=(short)f2bf_bits(f2.x); a1[1]=(short)f2bf_bits(f2.y);
        a1[2]=(short)f2bf_bits(f2.z); a1[3]=(short)f2bf_bits(f2.w);
        a1[4]=(short)f2bf_bits(f3.x); a1[5]=(short)f2bf_bits(f3.y);
        a1[6]=(short)f2bf_bits(f3.z); a1[7]=(short)f2bf_bits(f3.w);
        A0 = a0; A1 = a1;
    } else {
        const uint4* xr = (const uint4*)((const bf16*)xp + (size_t)nr * 64);
        A0 = __builtin_bit_cast(short8, xr[g]);
        A1 = __builtin_bit_cast(short8, xr[4 + g]);
    }

    float4v accq[4], acck[4], accv[4], accr[2];
    #pragma unroll
    for (int t = 0; t < 4; ++t) {
        float4v z = {0.f, 0.f, 0.f, 0.f};
        accq[t] = z; acck[t] = z; accv[t] = z;
        if (t < 2) accr[t] = z;
    }
    #pragma unroll
    for (int t = 0; t < 4; ++t) {
        accq[t] = __builtin_amdgcn_mfma_f32_16x16x32_bf16(A0, Bq[t][0], accq[t], 0, 0, 0);
        accq[t] = __builtin_amdgcn_mfma_f32_16x16x32_bf16(A1, Bq[t][1], accq[t], 0, 0, 0);
        acck[t] = __builtin_amdgcn_mfma_f32_16x16x32_bf16(A0, Bk[t][0], acck[t], 0, 0, 0);
        acck[t] = __builtin_amdgcn_mfma_f32_16x16x32_bf16(A1, Bk[t][1], acck[t], 0, 0, 0);
        accv[t] = __builtin_amdgcn_mfma_f32_16x16x32_bf16(A0, Bv[t][0], accv[t], 0, 0, 0);
        accv[t] = __builtin_amdgcn_mfma_f32_16x16x32_bf16(A1, Bv[t][1], accv[t], 0, 0, 0);
        if (t < 2) {
            accr[t] = __builtin_amdgcn_mfma_f32_16x16x32_bf16(A0, Br[t][0], accr[t], 0, 0, 0);
            accr[t] = __builtin_amdgcn_mfma_f32_16x16x32_bf16(A1, Br[t][1], accr[t], 0, 0, 0);
        }
    }

    #pragma unroll
    for (int t = 0; t < 4; ++t) {
        #pragma unroll
        for (int r = 0; r < 4; ++r) {
            int node = n0 + g * 4 + r;
            if (node < n_nodes) {
                v_out[(size_t)node * 64 + t * 16 + ml] = f2bf_bits(accv[t][r]);
                if (t < 2) r_out[(size_t)node * 32 + t * 16 + ml] = accr[t][r];
            }
        }
    }

    #pragma unroll
    for (int r = 0; r < 4; ++r) {
        float q0 = fast_tanh(accq[0][r] + embc[0]) * acq[0]
                 + fast_tanh(accq[1][r] + embc[1]) * acq[1];
        float q1 = fast_tanh(accq[2][r] + embc[2]) * acq[2]
                 + fast_tanh(accq[3][r] + embc[3]) * acq[3];
        float k0 = fast_tanh(acck[0][r] + embc[0]) * ack[0]
                 + fast_tanh(acck[1][r] + embc[1]) * ack[1];
        float k1 = fast_tanh(acck[2][r] + embc[2]) * ack[2]
                 + fast_tanh(acck[3][r] + embc[3]) * ack[3];
        #pragma unroll
        for (int o = 1; o < 16; o <<= 1) {
            q0 += __shfl_xor(q0, o, 64); q1 += __shfl_xor(q1, o, 64);
            k0 += __shfl_xor(k0, o, 64); k1 += __shfl_xor(k1, o, 64);
        }
        int node = n0 + g * 4 + r;
        if (ml == 0 && node < n_nodes) {
            sq_out[node] = make_float2(q0, q1);
            sk_out[node] = make_float2(k0, k1);
        }
    }
}

// ---------------- scans (CSR offsets) ----------------
__global__ __launch_bounds__(256) void scan1_kernel(const int* __restrict__ cnt,
                                                    int* __restrict__ partial, int n)
{
    __shared__ int wsum[4];
    int t = threadIdx.x;
    int i0 = blockIdx.x * 512 + 2 * t;
    int s = ((i0 < n) ? cnt[i0] : 0) + ((i0 + 1 < n) ? cnt[i0 + 1] : 0);
    #pragma unroll
    for (int o = 32; o; o >>= 1) s += __shfl_xor(s, o, 64);
    if ((t & 63) == 0) wsum[t >> 6] = s;
    __syncthreads();
    if (t == 0) partial[blockIdx.x] = wsum[0] + wsum[1] + wsum[2] + wsum[3];
}

__global__ void scan2_kernel(const int* __restrict__ partial, int* __restrict__ pp,
                             int* __restrict__ off, int nch, int noff)
{
    int lane = threadIdx.x;   // 64 threads
    int running = 0;
    for (int base = 0; base < nch; base += 64) {
        int i = base + lane;
        int o = (i < nch) ? partial[i] : 0;
        int v = o;
        #pragma unroll
        for (int d = 1; d < 64; d <<= 1) {
            int u = __shfl_up(v, d, 64);
            if (lane >= d) v += u;
        }
        if (i < nch) pp[i] = running + v - o;
        running += __shfl(v, 63, 64);
    }
    if (lane == 0) off[noff] = running;
}

__global__ __launch_bounds__(256) void scan3_kernel(const int* __restrict__ cnt,
                                                    const int* __restrict__ pp,
                                                    int* __restrict__ off, int n)
{
    __shared__ int tmp[256];
    int t = threadIdx.x;
    int i0 = blockIdx.x * 512 + 2 * t;
    int v0 = (i0 < n) ? cnt[i0] : 0;
    int v1 = (i0 + 1 < n) ? cnt[i0 + 1] : 0;
    int pair = v0 + v1;
    tmp[t] = pair;
    __syncthreads();
    for (int d = 1; d < 256; d <<= 1) {
        int x = (t >= d) ? tmp[t - d] : 0;
        __syncthreads();
        tmp[t] += x;
        __syncthreads();
    }
    int excl = tmp[t] - pair + pp[blockIdx.x];
    if (i0 < n)     off[i0] = excl;
    if (i0 + 1 < n) off[i0 + 1] = excl + v0;
}

// ---------------- fused edge scores + scatter, MFMA MLP, ZERO atomics -------------------
// Slot = offs[dst] + rank[e] (rank captured during histogram). All memory ops are
// plain loads/stores; the whole prologue pipelines.
// 48B CSR record per edge: {src, ex0, ex1, pad, ea[16] bf16}
__global__ __launch_bounds__(256) void edge_score_scatter_kernel(
    const void* __restrict__ ea1p, const void* __restrict__ ea2p,
    const unsigned short* __restrict__ wet,
    const int* __restrict__ row1, const int* __restrict__ col1,
    const int* __restrict__ row2, const int* __restrict__ col2,
    const float* __restrict__ sq_bp, const float* __restrict__ sk_ap,
    const float* __restrict__ sq_ap, const float* __restrict__ sk_bp,
    const float* __restrict__ cvals, const void* __restrict__ a_attn,
    const int* __restrict__ flagp,
    const int* __restrict__ offs, const int* __restrict__ rankp,
    uint4* __restrict__ payload, int n_nodes, int num_e)
{
    const int f32 = *flagp;
    const int sel = blockIdx.x & 1;
    const int bx  = blockIdx.x >> 1;
    const void* ea = sel ? ea2p : ea1p;
    const int* row = sel ? row2 : row1;
    const int* col = sel ? col2 : col1;
    const float* sq_dst = sel ? sq_ap : sq_bp;
    const float* sk_src = sel ? sk_bp : sk_ap;
    const int rb = sel ? n_nodes : 0;
    const int* rankr = rankp + (size_t)sel * num_e;

    const int lane = threadIdx.x & 63;
    const int wv   = threadIdx.x >> 6;
    const int ml   = lane & 15;
    const int g    = lane >> 4;
    const int rsel = lane & 3;

    const int base = bx * 256 + wv * 64;
    if (base >= num_e) return;                        // uniform per wave

    const short8 zero8 = {0, 0, 0, 0, 0, 0, 0, 0};

    // B-fragments: B[k][n=t*16+ml], k = g*8..g*8+7 (<16 real, else 0)
    short8 B[4];
    #pragma unroll
    for (int t = 0; t < 4; ++t)
        B[t] = (g < 2) ? __builtin_bit_cast(short8, *(const uint4*)(wet + (t * 16 + ml) * 16 + g * 8))
                       : zero8;
    float av[4];
    #pragma unroll
    for (int t = 0; t < 4; ++t) av[t] = ldf(a_attn, 96 + ((t * 16 + ml) & 31), f32);
    const float c0 = cvals[sel * 2 + 0];
    const float c1 = cvals[sel * 2 + 1];

    // ---- prologue 1: metadata (finalize lanes ml<4) -- issue earliest ----
    int pcol[4]; unsigned psrc[4]; int prank[4];
    #pragma unroll
    for (int it = 0; it < 4; ++it) { pcol[it] = 0; psrc[it] = 0; prank[it] = 0; }
    if (ml < 4) {
        #pragma unroll
        for (int it = 0; it < 4; ++it) {
            int e = base + it * 16 + g * 4 + rsel;
            int ec = (e < num_e) ? e : (num_e - 1);
            pcol[it]  = col[ec];
            psrc[it]  = (unsigned)row[ec];
            prank[it] = rankr[ec];
        }
    }

    // ---- prologue 2: A-fragments for all 4 tiles (coalesced ea stream) ----
    short8 A[4];
    #pragma unroll
    for (int it = 0; it < 4; ++it) {
        int ec = base + it * 16 + ml; if (ec > num_e - 1) ec = num_e - 1;
        if (g < 2) {
            if (f32) {
                const float4* p = (const float4*)((const float*)ea + (size_t)ec * 16 + g * 8);
                float4 f0 = p[0], f1 = p[1];
                short8 a;
                a[0] = (short)f2bf_bits(f0.x); a[1] = (short)f2bf_bits(f0.y);
                a[2] = (short)f2bf_bits(f0.z); a[3] = (short)f2bf_bits(f0.w);
                a[4] = (short)f2bf_bits(f1.x); a[5] = (short)f2bf_bits(f1.y);
                a[6] = (short)f2bf_bits(f1.z); a[7] = (short)f2bf_bits(f1.w);
                A[it] = a;
            } else {
                A[it] = __builtin_bit_cast(short8, *(const uint4*)((const bf16*)ea + (size_t)ec * 16 + g * 8));
            }
        } else {
            A[it] = zero8;
        }
    }

    // ---- prologue 3: dependent gathers (sq/sk + CSR slot), no atomics ----
    int ppos[4]; float2 psq[4], psk[4];
    #pragma unroll
    for (int it = 0; it < 4; ++it) {
        ppos[it] = 0;
        psq[it] = make_float2(0.f, 0.f); psk[it] = make_float2(0.f, 0.f);
    }
    if (ml < 4) {
        #pragma unroll
        for (int it = 0; it < 4; ++it) {
            psq[it] = ((const float2*)sq_dst)[pcol[it]];
            psk[it] = ((const float2*)sk_src)[psrc[it]];
            ppos[it] = offs[rb + pcol[it]] + prank[it];
        }
    }

    // ---- compute sweep: no long-latency op on the critical path ----
    #pragma unroll
    for (int it = 0; it < 4; ++it) {
        const int e0 = base + it * 16;
        if (e0 < num_e) {
            float4v z = {0.f, 0.f, 0.f, 0.f};
            float4v acc0 = z, acc1 = z, acc2 = z, acc3 = z;
            acc0 = __builtin_amdgcn_mfma_f32_16x16x32_bf16(A[it], B[0], acc0, 0, 0, 0);
            acc1 = __builtin_amdgcn_mfma_f32_16x16x32_bf16(A[it], B[1], acc1, 0, 0, 0);
            acc2 = __builtin_amdgcn_mfma_f32_16x16x32_bf16(A[it], B[2], acc2, 0, 0, 0);
            acc3 = __builtin_amdgcn_mfma_f32_16x16x32_bf16(A[it], B[3], acc3, 0, 0, 0);

            // per-lane partials: s0/s1[r] for edges g*4+r, heads 0/1
            float s0[4], s1[4];
            #pragma unroll
            for (int r = 0; r < 4; ++r) {
                s0[r] = fast_tanh(acc0[r]) * av[0] + fast_tanh(acc1[r]) * av[1];
                s1[r] = fast_tanh(acc2[r]) * av[2] + fast_tanh(acc3[r]) * av[3];
            }
            // butterfly over the 16-lane column group
            #pragma unroll
            for (int o = 1; o < 16; o <<= 1) {
                #pragma unroll
                for (int r = 0; r < 4; ++r) {
                    s0[r] += __shfl_xor(s0[r], o, 64);
                    s1[r] += __shfl_xor(s1[r], o, 64);
                }
            }

            const bool fin = (ml < 4) && (e0 + g * 4 + rsel < num_e);
            if (fin) {
                float a0 = (rsel == 0) ? s0[0] : (rsel == 1) ? s0[1] : (rsel == 2) ? s0[2] : s0[3];
                float a1 = (rsel == 0) ? s1[0] : (rsel == 1) ? s1[1] : (rsel == 2) ? s1[2] : s1[3];
                float v0 = fminf(30.f, fmaxf(-30.f, a0 + psq[it].x + psk[it].x + c0));
                float v1 = fminf(30.f, fmaxf(-30.f, a1 + psq[it].y + psk[it].y + c1));
                uint4* rec = payload + (size_t)3 * ppos[it];
                rec[0] = make_uint4(psrc[it], __float_as_uint(__expf(v0)),
                                    __float_as_uint(__expf(v1)), 0u);
            }
            // writer lane l (<32) targets edge ml=l&15; its finalize lane is
            // ((ml>>2)*16 + (ml&3)) = ((l&12)<<2) | (l&3)
            const int srcl = ((lane & 12) << 2) | (lane & 3);
            const int posx = __shfl(ppos[it], srcl, 64);
            if (lane < 32 && (e0 + ml < num_e)) {
                uint4* rec = payload + (size_t)3 * posx;
                rec[1 + g] = __builtin_bit_cast(uint4, A[it]);   // ea bf16 halves
            }
        }
    }
}

// ---------------- fused aggregation + output projection (both relations, XCD-split) -----
__global__ __launch_bounds__(256) void agg_final_kernel(
    const uint4* __restrict__ payload, const int* __restrict__ off,
    const unsigned short* __restrict__ v_a, const unsigned short* __restrict__ v_b,
    const float* __restrict__ r_a, const float* __restrict__ r_b,
    const void* __restrict__ Wo_a, const void* __restrict__ Wo_b,
    const void* __restrict__ bo_a, const void* __restrict__ bo_b,
    const float* __restrict__ M1, const float* __restrict__ M2,
    const float* __restrict__ c321, const float* __restrict__ c322,
    const int* __restrict__ flagp, void* __restrict__ out,
    int n_nodes, int nbh)
{
    const int sel = blockIdx.x & 1;                 // 0: rel1 (dst=b), 1: rel2 (dst=a)
    const int bx  = blockIdx.x >> 1;
    const unsigned short* v_src = sel ? v_b : v_a;
    const float* r_src = sel ? r_a : r_b;           // residual of DST type
    const void*  Wo    = sel ? Wo_a : Wo_b;
    const void*  bo    = sel ? bo_a : bo_b;
    const float* M     = sel ? M2 : M1;
    const float* c32   = sel ? c322 : c321;
    const int relbase  = sel ? n_nodes : 0;
    const size_t out_off = sel ? 0 : (size_t)n_nodes * 32;

    const int f32  = *flagp;
    const int lane = threadIdx.x & 63;
    const int wv   = threadIdx.x >> 6;
    const int j    = lane & 31;
    const int half = lane >> 5;
    const int c16  = lane & 15;
    const bool hi  = (lane >= 32);

    __shared__ float stage[4][96];   // per-wave: y[64] | u[32]

    float WoR[32], MR[16];
    const int cb = half * 32;
    #pragma unroll
    for (int cc = 0; cc < 32; ++cc)
        WoR[cc] = ldf(Wo, (size_t)(cb + cc) * 32 + j, f32);
    const int ub = half * 16;
    #pragma unroll
    for (int cc = 0; cc < 16; ++cc) MR[cc] = M[(ub + cc) * 32 + j];
    const float boR  = ldf(bo, j, f32);
    const float c32R = c32[j];

    const int stride = nbh * 4;
    const int iters  = (n_nodes + stride - 1) / stride;
    int d = bx * 4 + wv;

    // software pipeline: preload iteration 0's offsets + residual
    int dd0 = (d < n_nodes) ? d : (n_nodes - 1);
    int b_c  = off[relbase + dd0];
    int en_c = off[relbase + dd0 + 1];
    float rv_c = r_src[(size_t)dd0 * 32 + j];

    for (int it = 0; it < iters; ++it, d += stride) {
        const bool valid = (d < n_nodes);
        const int dd  = valid ? d : (n_nodes - 1);

        // issue next iteration's loads early (hide under the edge loop)
        int b_n = 0, en_n = 0; float rv_n = 0.f;
        if (it + 1 < iters) {
            int dn  = d + stride;
            int ddn = (dn < n_nodes) ? dn : (n_nodes - 1);
            b_n  = off[relbase + ddn];
            en_n = off[relbase + ddn + 1];
            rv_n = r_src[(size_t)ddn * 32 + j];
        }

        const int b   = __builtin_amdgcn_readfirstlane(b_c);
        const int en  = __builtin_amdgcn_readfirstlane(en_c);
        const int deg = en - b;
        const float rv = rv_c;

        float den0 = 0.f, den1 = 0.f, y = 0.f, ua = 0.f;
        int k = b;
        #pragma unroll 1
        for (; k + 8 <= en; k += 8) {
            uint4 m[8];
            #pragma unroll
            for (int q = 0; q < 8; ++q) m[q] = payload[(size_t)3 * (k + q)];
            float ev[8];
            #pragma unroll
            for (int q = 0; q < 8; ++q) {
                const unsigned short* pq = (const unsigned short*)(payload + (size_t)3 * (k + q) + 1);
                ev[q] = __uint_as_float((unsigned)pq[c16] << 16);
            }
            float vv[8];
            #pragma unroll
            for (int q = 0; q < 8; ++q)
                vv[q] = __uint_as_float((unsigned)v_src[(size_t)m[q].x * 64 + lane] << 16);
            #pragma unroll
            for (int q = 0; q < 8; ++q) {
                float e0 = __uint_as_float(m[q].y), e1 = __uint_as_float(m[q].z);
                den0 += e0; den1 += e1;
                float xw = hi ? e1 : e0;
                y  = fmaf(xw, vv[q], y);
                ua = fmaf(xw, ev[q], ua);
            }
        }
        #pragma unroll 1
        for (; k < en; ++k) {
            uint4 mm = payload[(size_t)3 * k];
            const unsigned short* pq = (const unsigned short*)(payload + (size_t)3 * k + 1);
            float evs = __uint_as_float((unsigned)pq[c16] << 16);
            float vvs = __uint_as_float((unsigned)v_src[(size_t)mm.x * 64 + lane] << 16);
            float e0 = __uint_as_float(mm.y), e1 = __uint_as_float(mm.z);
            den0 += e0; den1 += e1;
            float xw = hi ? e1 : e0;
            y  = fmaf(xw, vvs, y);
            ua = fmaf(xw, evs, ua);
        }

        float inv0 = (deg > 0) ? __builtin_amdgcn_rcpf(den0) : 0.f;
        float inv1 = (deg > 0) ? __builtin_amdgcn_rcpf(den1) : 0.f;
        const float invh = hi ? inv1 : inv0;
        y  *= invh;
        ua *= invh;

        // wave-private LDS staging (lockstep wave64 + lgkmcnt drain).
        float* st = stage[wv];
        st[lane] = y;
        if ((lane & 31) < 16) st[64 + half * 16 + c16] = ua;
        __asm__ volatile("s_waitcnt lgkmcnt(0)" ::: "memory");

        float acc = 0.f;
        #pragma unroll
        for (int cc = 0; cc < 32; ++cc)
            acc = fmaf(st[cb + cc], WoR[cc], acc);
        #pragma unroll
        for (int cc = 0; cc < 16; ++cc)
            acc = fmaf(st[64 + ub + cc], MR[cc], acc);

        float other = __shfl(acc, lane ^ 32, 64);
        if (valid && lane < 32) {
            float o = acc + other + boR + rv + ((deg > 0) ? c32R : 0.f);
            stf(out, out_off + (size_t)dd * 32 + j, f32, o);
        }
        __asm__ volatile("" ::: "memory");
        __builtin_amdgcn_wave_barrier();

        b_c = b_n; en_c = en_n; rv_c = rv_n;
    }
}

extern "C" void kernel_launch(void* const* d_in, const int* in_sizes, int n_in,
                              void* d_out, int out_size, void* d_ws, size_t ws_size,
                              hipStream_t stream)
{
    const void* x_a   = d_in[0];
    const void* x_b   = d_in[1];
    const void* ea1   = d_in[2];
    const void* ea2   = d_in[3];
    const void* Wq_a  = d_in[4];
    const void* Wk_a  = d_in[5];
    const void* Wv_a  = d_in[6];
    const void* Wq_b  = d_in[7];
    const void* Wk_b  = d_in[8];
    const void* Wv_b  = d_in[9];
    const void* emb_a = d_in[10];
    const void* emb_b = d_in[11];
    const void* rel1  = d_in[12];
    const void* rel2  = d_in[13];
    const void* We    = d_in[14];
    const void* a_at  = d_in[15];
    const void* Wo_a  = d_in[16];
    const void* bo_a  = d_in[17];
    const void* Wo_b  = d_in[18];
    const void* bo_b  = d_in[19];
    const void* Wr_a  = d_in[20];
    const void* Wr_b  = d_in[21];
    const int*  row1  = (const int*)d_in[22];
    const int*  col1  = (const int*)d_in[23];
    const int*  row2  = (const int*)d_in[24];
    const int*  col2  = (const int*)d_in[25];

    const int N = in_sizes[0] / 64;   // nodes per type
    const int E = in_sizes[22];       // edges per relation

    // ---- workspace layout (float units) ----
    float* ws = (float*)d_ws;
    size_t off = 0;
    int*   flag = (int*)ws;        off += 64;
    unsigned short* v_a = (unsigned short*)(ws + off); off += (size_t)N * 32;  // bf16 N x 64
    unsigned short* v_b = (unsigned short*)(ws + off); off += (size_t)N * 32;
    float* r_a  = ws + off;        off += (size_t)N * 32;
    float* r_b  = ws + off;        off += (size_t)N * 32;
    float* sq_a = ws + off;        off += (size_t)N * 2;
    float* sk_a = ws + off;        off += (size_t)N * 2;
    float* sq_b = ws + off;        off += (size_t)N * 2;
    float* sk_b = ws + off;        off += (size_t)N * 2;
    float* cvals = ws + off;       off += 4;
    off = (off + 3) & ~(size_t)3;  // 16B align
    unsigned short* wt = (unsigned short*)(ws + off); off += 29696 / 2;  // 6x4096+2x2048+1024 bf16
    float* M1   = ws + off;        off += 1024;
    float* c321 = ws + off;        off += 32;
    float* M2   = ws + off;        off += 1024;
    float* c322 = ws + off;        off += 32;
    int*   cnt    = (int*)(ws + off);  off += (size_t)2 * N;
    int*   offs   = (int*)(ws + off);  off += (size_t)2 * N + 2;
    int*   rankp  = (int*)(ws + off);  off += (size_t)2 * E;
    int*   partial = (int*)(ws + off); off += 512;
    int*   pp      = (int*)(ws + off); off += 512;
    off = (off + 3) & ~(size_t)3;     // 16B align for uint4
    uint4* payload = (uint4*)(ws + off); off += (size_t)2 * E * 12;  // 48B records

    const int tiles        = (N + 15) >> 4;
    const int mfma_blocks  = (2 * tiles + 3) / 4;
    const int eb_blocks    = (E + 255) / 256;
    const int score_blocks = (E + 255) / 256;           // 256 edges per block (4 waves x 64)
    const int nch          = (2 * N + 511) / 512;
    const int agg_half     = 4096;                      // blocks per relation

    detect_kernel<<<1, 128, 0, stream>>>((const unsigned short*)a_at, flag);
    hipMemsetAsync(cnt, 0, (size_t)2 * N * sizeof(int), stream);

    prep_small_kernel<<<11, 256, 0, stream>>>(
        Wq_a, Wk_a, Wv_a, Wq_b, Wk_b, Wv_b, Wr_a, Wr_b,
        We, Wo_a, Wo_b, rel1, rel2, a_at, flag,
        wt, M1, c321, M2, c322, cvals);

    // node prep + fused histogram with rank capture (extra blocks)
    node_prep_mfma_kernel<<<mfma_blocks + 2 * eb_blocks, 256, 0, stream>>>(
        x_a, x_b, wt, emb_a, emb_b, a_at, flag,
        v_a, v_b, r_a, r_b, sq_a, sk_a, sq_b, sk_b,
        col1, col2, cnt, rankp, N, tiles, mfma_blocks, E);

    scan1_kernel<<<nch, 256, 0, stream>>>(cnt, partial, 2 * N);
    scan2_kernel<<<1, 64, 0, stream>>>(partial, pp, offs, nch, 2 * N);
    scan3_kernel<<<nch, 256, 0, stream>>>(cnt, pp, offs, 2 * N);

    edge_score_scatter_kernel<<<2 * score_blocks, 256, 0, stream>>>(
        ea1, ea2, wt + 28672, row1, col1, row2, col2,
        sq_b, sk_a, sq_a, sk_b, cvals, a_at, flag,
        offs, rankp, payload, N, E);

    agg_final_kernel<<<2 * agg_half, 256, 0, stream>>>(
        payload, offs, v_a, v_b, r_a, r_b, Wo_a, Wo_b, bo_a, bo_b,
        M1, M2, c321, c322, flag, d_out, N, agg_half);
}